// Round 1
// baseline (1076.652 us; speedup 1.0000x reference)
//
#include <hip/hip_runtime.h>
#include <hip/hip_bf16.h>
#include <math.h>

#define N_PAT 256
#define VIS   5
#define NV    (N_PAT*VIS)   // 1280 rows
#define DD    48            // codes per visit per modality
#define CD    128           // code dim C
#define DT    256
#define NHD   8
#define HD    32
#define DFF   2048
#define REP   128

// ---------------- positional encoding (5 x 256) ----------------
__global__ void pe_kernel(float* __restrict__ pe) {
    int pos = blockIdx.x, c = threadIdx.x;
    int j = c >> 1;
    float ang = (float)pos / powf(10000.f, (2.f * (float)j) / 256.f);
    pe[pos * DT + c] = (c & 1) ? cosf(ang) : sinf(ang);
}

// ---------------- GRAM: code-level + visit-level attention ----------------
// one block per (n,v); wave w handles codes w, w+4, ...; lane l owns channels 2l,2l+1
__global__ __launch_bounds__(256) void gram_kernel(
    const int* __restrict__ xd1, const int* __restrict__ xd2, const int* __restrict__ xd3,
    const int* __restrict__ xr1, const int* __restrict__ xr2, const int* __restrict__ xr3,
    const int* __restrict__ xr4,
    const float* __restrict__ Ed1, const float* __restrict__ Ed2, const float* __restrict__ Ed3,
    const float* __restrict__ Er1, const float* __restrict__ Er2, const float* __restrict__ Er3,
    const float* __restrict__ Er4,
    const float* __restrict__ We_dx, const float* __restrict__ be_dx,
    const float* __restrict__ We_rx, const float* __restrict__ be_rx,
    const float* __restrict__ Wev_dx, const float* __restrict__ bev_dx,
    const float* __restrict__ Wev_rx, const float* __restrict__ bev_rx,
    float* __restrict__ ccv)
{
    __shared__ float ctx[96][128];  // 48 dx + 48 rx context vectors
    __shared__ float ev[96];        // visit-attention logits -> weights
    const int nv   = blockIdx.x;
    const int tid  = threadIdx.x;
    const int wave = tid >> 6, lane = tid & 63;
    const int base = nv * DD;

    // ---- dx codes (3 levels) ----
    for (int d = wave; d < DD; d += 4) {
        int i1 = xd1[base + d], i2 = xd2[base + d], i3 = xd3[base + d];
        float2 e1 = *(const float2*)(Ed1 + (size_t)i1 * CD + lane * 2);
        float2 e2 = *(const float2*)(Ed2 + (size_t)i2 * CD + lane * 2);
        float2 e3 = *(const float2*)(Ed3 + (size_t)i3 * CD + lane * 2);
        float2 wl = *(const float2*)(We_dx + lane * 2);
        float2 wh = *(const float2*)(We_dx + CD + lane * 2);
        float p0 = e3.x * wl.x + e3.y * wl.y;   // dot(emb3, We_lo)
        float p1 = e1.x * wh.x + e1.y * wh.y;
        float p2 = e2.x * wh.x + e2.y * wh.y;
        float p3 = e3.x * wh.x + e3.y * wh.y;
        #pragma unroll
        for (int off = 32; off; off >>= 1) {
            p0 += __shfl_xor(p0, off, 64);
            p1 += __shfl_xor(p1, off, 64);
            p2 += __shfl_xor(p2, off, 64);
            p3 += __shfl_xor(p3, off, 64);
        }
        float be = be_dx[0];
        float s1 = fmaxf(p0 + p1 + be, 0.f);
        float s2 = fmaxf(p0 + p2 + be, 0.f);
        float s3 = fmaxf(p0 + p3 + be, 0.f);
        float a1, a2, a3;
        if (i1 != 0) {
            float mx = fmaxf(s1, fmaxf(s2, s3));
            a1 = expf(s1 - mx); a2 = expf(s2 - mx); a3 = expf(s3 - mx);
        } else {            // masked: softmax of equal NEG values = uniform
            a1 = a2 = a3 = 1.f;
        }
        float inv = 1.f / (a1 + a2 + a3);
        a1 *= inv; a2 *= inv; a3 *= inv;
        float cx = a1 * e1.x + a2 * e2.x + a3 * e3.x;
        float cy = a1 * e1.y + a2 * e2.y + a3 * e3.y;
        ctx[d][lane * 2]     = cx;
        ctx[d][lane * 2 + 1] = cy;
        float2 wv = *(const float2*)(Wev_dx + lane * 2);
        float pv = cx * wv.x + cy * wv.y;
        #pragma unroll
        for (int off = 32; off; off >>= 1) pv += __shfl_xor(pv, off, 64);
        if (lane == 0) ev[d] = (i1 != 0) ? (pv + bev_dx[0]) : -1e20f;
    }

    // ---- rx codes (4 levels) ----
    for (int d = wave; d < DD; d += 4) {
        int i1 = xr1[base + d], i2 = xr2[base + d], i3 = xr3[base + d], i4 = xr4[base + d];
        float2 e1 = *(const float2*)(Er1 + (size_t)i1 * CD + lane * 2);
        float2 e2 = *(const float2*)(Er2 + (size_t)i2 * CD + lane * 2);
        float2 e3 = *(const float2*)(Er3 + (size_t)i3 * CD + lane * 2);
        float2 e4 = *(const float2*)(Er4 + (size_t)i4 * CD + lane * 2);
        float2 wl = *(const float2*)(We_rx + lane * 2);
        float2 wh = *(const float2*)(We_rx + CD + lane * 2);
        float p0 = e4.x * wl.x + e4.y * wl.y;   // dot(emb4, We_lo)
        float p1 = e1.x * wh.x + e1.y * wh.y;
        float p2 = e2.x * wh.x + e2.y * wh.y;
        float p3 = e3.x * wh.x + e3.y * wh.y;
        float p4 = e4.x * wh.x + e4.y * wh.y;
        #pragma unroll
        for (int off = 32; off; off >>= 1) {
            p0 += __shfl_xor(p0, off, 64);
            p1 += __shfl_xor(p1, off, 64);
            p2 += __shfl_xor(p2, off, 64);
            p3 += __shfl_xor(p3, off, 64);
            p4 += __shfl_xor(p4, off, 64);
        }
        float be = be_rx[0];
        float s1 = fmaxf(p0 + p1 + be, 0.f);
        float s2 = fmaxf(p0 + p2 + be, 0.f);
        float s3 = fmaxf(p0 + p3 + be, 0.f);
        float s4 = fmaxf(p0 + p4 + be, 0.f);
        float a1, a2, a3, a4;
        if (i1 != 0) {
            float mx = fmaxf(fmaxf(s1, s2), fmaxf(s3, s4));
            a1 = expf(s1 - mx); a2 = expf(s2 - mx); a3 = expf(s3 - mx); a4 = expf(s4 - mx);
        } else {
            a1 = a2 = a3 = a4 = 1.f;
        }
        float inv = 1.f / (a1 + a2 + a3 + a4);
        a1 *= inv; a2 *= inv; a3 *= inv; a4 *= inv;
        float cx = a1 * e1.x + a2 * e2.x + a3 * e3.x + a4 * e4.x;
        float cy = a1 * e1.y + a2 * e2.y + a3 * e3.y + a4 * e4.y;
        ctx[DD + d][lane * 2]     = cx;
        ctx[DD + d][lane * 2 + 1] = cy;
        float2 wv = *(const float2*)(Wev_rx + lane * 2);
        float pv = cx * wv.x + cy * wv.y;
        #pragma unroll
        for (int off = 32; off; off >>= 1) pv += __shfl_xor(pv, off, 64);
        if (lane == 0) ev[DD + d] = (i1 != 0) ? (pv + bev_rx[0]) : -1e20f;
    }
    __syncthreads();

    // ---- visit-level softmax over the 96 logits (wave 0) ----
    if (wave == 0) {
        float a = ev[lane];
        float b = (lane < 32) ? ev[64 + lane] : -3.0e38f;
        float mx = fmaxf(a, b);
        #pragma unroll
        for (int off = 32; off; off >>= 1) mx = fmaxf(mx, __shfl_xor(mx, off, 64));
        float ea = expf(a - mx);
        float eb = (lane < 32) ? expf(b - mx) : 0.f;
        float s = ea + eb;
        #pragma unroll
        for (int off = 32; off; off >>= 1) s += __shfl_xor(s, off, 64);
        float inv = 1.f / s;
        ev[lane] = ea * inv;
        if (lane < 32) ev[64 + lane] = eb * inv;
    }
    __syncthreads();

    // ---- ccv[c] = sum_m att[m] * ctx[m][c] ----
    if (tid < CD) {
        float acc = 0.f;
        #pragma unroll 8
        for (int m = 0; m < 96; ++m) acc += ev[m] * ctx[m][tid];
        ccv[(size_t)nv * CD + tid] = acc;
    }
}

// ---------------- build x0 = [relu(x_demo@W_demo+b), ccv] : [1280,192] ----------------
__global__ __launch_bounds__(192) void build_x0(
    const float* __restrict__ x_demo, const float* __restrict__ W_demo,
    const float* __restrict__ b_demo, const float* __restrict__ ccv,
    float* __restrict__ A0)
{
    int row = blockIdx.x, j = threadIdx.x;
    if (j < 64) {
        float acc = b_demo[j];
        #pragma unroll
        for (int f = 0; f < 32; ++f) acc += x_demo[row * 32 + f] * W_demo[f * 64 + j];
        A0[row * 192 + j] = fmaxf(acc, 0.f);
    } else {
        A0[row * 192 + j] = ccv[row * CD + (j - 64)];
    }
}

// ---------------- tiled f32 GEMM: C = act(A@B + bias [+ pe(row%5)]) ----------------
// A [M,K] row-major, B [K,N] row-major. BM=BN=64, BK=16, 256 thr, 4x4 microtile.
__global__ __launch_bounds__(256) void gemm_k(
    const float* __restrict__ A, const float* __restrict__ B,
    const float* __restrict__ bias, const float* __restrict__ pe,
    float* __restrict__ C, int M, int N, int K, int relu)
{
    __shared__ float As[16][68];   // [k][m], pad 68 -> conflict-free stores, 16B-aligned rows
    __shared__ float Bs[16][64];   // [k][n]
    const int bm = blockIdx.y * 64, bn = blockIdx.x * 64;
    const int tid = threadIdx.x;
    const int tx = tid & 15, ty = tid >> 4;
    float acc[4][4] = {{0.f}};

    for (int k0 = 0; k0 < K; k0 += 16) {
        {   // A tile: 64 rows x 16 k
            int c = tid & 15, r0 = tid >> 4;
            #pragma unroll
            for (int j = 0; j < 4; ++j) {
                int r = r0 + j * 16;
                As[c][r] = A[(size_t)(bm + r) * K + k0 + c];
            }
        }
        {   // B tile: 16 k x 64 cols
            int bc = tid & 63, br0 = tid >> 6;
            #pragma unroll
            for (int j = 0; j < 4; ++j) {
                int br = br0 + j * 4;
                Bs[br][bc] = B[(size_t)(k0 + br) * N + bn + bc];
            }
        }
        __syncthreads();
        #pragma unroll
        for (int kk = 0; kk < 16; ++kk) {
            float a[4], b[4];
            #pragma unroll
            for (int i = 0; i < 4; ++i) a[i] = As[kk][ty * 4 + i];
            #pragma unroll
            for (int i = 0; i < 4; ++i) b[i] = Bs[kk][tx * 4 + i];
            #pragma unroll
            for (int i = 0; i < 4; ++i)
                #pragma unroll
                for (int j = 0; j < 4; ++j)
                    acc[i][j] += a[i] * b[j];
        }
        __syncthreads();
    }

    #pragma unroll
    for (int i = 0; i < 4; ++i) {
        int row = bm + ty * 4 + i;
        #pragma unroll
        for (int j = 0; j < 4; ++j) {
            int col = bn + tx * 4 + j;
            float v = acc[i][j] + bias[col];
            if (pe) v += pe[(row % VIS) * N + col];
            if (relu) v = fmaxf(v, 0.f);
            C[(size_t)row * N + col] = v;
        }
    }
}

// ---------------- attention: seq=5, 8 heads, hd=32; block per n, 32 thr per head ----------------
__global__ __launch_bounds__(256) void attn_kernel(
    const float* __restrict__ qkv, float* __restrict__ out)
{
    const int n = blockIdx.x;
    const int tid = threadIdx.x;
    const int h = tid >> 5, t = tid & 31;
    float q[VIS], k[VIS], v[VIS];
    #pragma unroll
    for (int j = 0; j < VIS; ++j) {
        const float* row = qkv + (size_t)(n * VIS + j) * 768 + h * HD + t;
        q[j] = row[0]; k[j] = row[256]; v[j] = row[512];
    }
    const float scale = 0.1767766952966369f;  // 1/sqrt(32)
    float s[VIS][VIS];
    #pragma unroll
    for (int qi = 0; qi < VIS; ++qi)
        #pragma unroll
        for (int ki = 0; ki < VIS; ++ki) {
            float p = q[qi] * k[ki];
            #pragma unroll
            for (int off = 16; off; off >>= 1) p += __shfl_xor(p, off, 32);
            s[qi][ki] = p * scale;
        }
    #pragma unroll
    for (int qi = 0; qi < VIS; ++qi) {
        float mx = s[qi][0];
        #pragma unroll
        for (int ki = 1; ki < VIS; ++ki) mx = fmaxf(mx, s[qi][ki]);
        float e[VIS], sum = 0.f;
        #pragma unroll
        for (int ki = 0; ki < VIS; ++ki) { e[ki] = expf(s[qi][ki] - mx); sum += e[ki]; }
        float inv = 1.f / sum;
        float acc = 0.f;
        #pragma unroll
        for (int ki = 0; ki < VIS; ++ki) acc += e[ki] * inv * v[ki];
        out[(size_t)(n * VIS + qi) * DT + h * HD + t] = acc;
    }
}

// ---------------- residual-add + LayerNorm over 256, block per row ----------------
__global__ __launch_bounds__(256) void ln_kernel(
    const float* __restrict__ x, const float* __restrict__ r,
    const float* __restrict__ s, const float* __restrict__ b,
    float* __restrict__ out)
{
    const int row = blockIdx.x, t = threadIdx.x;
    float v = x[(size_t)row * DT + t] + r[(size_t)row * DT + t];
    float s1 = v, s2 = v * v;
    #pragma unroll
    for (int off = 32; off; off >>= 1) {
        s1 += __shfl_xor(s1, off, 64);
        s2 += __shfl_xor(s2, off, 64);
    }
    __shared__ float red[2][4];
    int wave = t >> 6, lane = t & 63;
    if (lane == 0) { red[0][wave] = s1; red[1][wave] = s2; }
    __syncthreads();
    s1 = red[0][0] + red[0][1] + red[0][2] + red[0][3];
    s2 = red[1][0] + red[1][1] + red[1][2] + red[1][3];
    float m   = s1 * (1.f / 256.f);
    float var = s2 * (1.f / 256.f) - m * m;
    float inv = 1.f / sqrtf(var + 1e-5f);
    out[(size_t)row * DT + t] = (v - m) * inv * s[t] + b[t];
}

// ---------------- visit compression + ph MLP; block per n, 128 thr ----------------
__global__ __launch_bounds__(128) void vc_ph_kernel(
    const float* __restrict__ enc, const float* __restrict__ Wcv, const float* __restrict__ bcv,
    const float* __restrict__ mlp_w, const float* __restrict__ mlp_b,
    const float* __restrict__ mlp2_w, const float* __restrict__ mlp2_b,
    float* __restrict__ civ_out, float* __restrict__ ph_out)
{
    const int n = blockIdx.x, t = threadIdx.x;
    const int wave = t >> 6, lane = t & 63;
    float e[VIS];
    #pragma unroll
    for (int v = 0; v < VIS; ++v) e[v] = enc[(size_t)(n * VIS + v) * REP + t];
    float w = Wcv[t];
    __shared__ float part[VIS][2];
    #pragma unroll
    for (int v = 0; v < VIS; ++v) {
        float pv = e[v] * w;
        #pragma unroll
        for (int off = 32; off; off >>= 1) pv += __shfl_xor(pv, off, 64);
        if (lane == 0) part[v][wave] = pv;
    }
    __syncthreads();
    float b0 = bcv[0];
    float sc[VIS], mx = -3e38f;
    #pragma unroll
    for (int v = 0; v < VIS; ++v) { sc[v] = part[v][0] + part[v][1] + b0; mx = fmaxf(mx, sc[v]); }
    float sum = 0.f;
    #pragma unroll
    for (int v = 0; v < VIS; ++v) { sc[v] = expf(sc[v] - mx); sum += sc[v]; }
    float inv = 1.f / sum;
    float civ = 0.f;
    #pragma unroll
    for (int v = 0; v < VIS; ++v) civ += sc[v] * inv * e[v];
    civ_out[(size_t)n * REP + t] = civ;

    __shared__ float civ_s[REP];
    __shared__ float h1_s[64];
    civ_s[t] = civ;
    __syncthreads();
    if (t < 64) {
        float acc = mlp_b[t];
        #pragma unroll 8
        for (int c = 0; c < REP; ++c) acc += civ_s[c] * mlp_w[c * 64 + t];
        h1_s[t] = fmaxf(acc, 0.f);
    }
    __syncthreads();
    if (t < 64) {
        float acc = mlp2_b[t];
        #pragma unroll 8
        for (int j = 0; j < 64; ++j) acc += h1_s[j] * mlp2_w[j * 64 + t];
        ph_out[(size_t)n * 64 + t] = acc;
    }
}

// ---------------- per-event FC heads; block per (n,e), 256 thr ----------------
__global__ __launch_bounds__(256) void heads_kernel(
    const float* __restrict__ civ,
    const float* __restrict__ fc1w, const float* __restrict__ fc1b,
    const float* __restrict__ fc2w, const float* __restrict__ fc2b,
    const float* __restrict__ fc3w, const float* __restrict__ fc3b,
    float* __restrict__ out)
{
    const int n = blockIdx.x >> 1, e = blockIdx.x & 1;
    const int t = threadIdx.x;
    __shared__ float civ_s[REP], h1[256], h2[128];
    if (t < REP) civ_s[t] = civ[(size_t)n * REP + t];
    __syncthreads();
    {
        float acc = fc1b[e * 256 + t];
        const float* w = fc1w + (size_t)e * REP * 256;
        #pragma unroll 8
        for (int c = 0; c < REP; ++c) acc += civ_s[c] * w[c * 256 + t];
        h1[t] = fmaxf(acc, 0.f);
    }
    __syncthreads();
    if (t < 128) {
        float acc = fc2b[e * 128 + t];
        const float* w = fc2w + (size_t)e * 256 * 128;
        #pragma unroll 8
        for (int c = 0; c < 256; ++c) acc += h1[c] * w[c * 128 + t];
        h2[t] = fmaxf(acc, 0.f);
    }
    __syncthreads();
    if (t < 64) {
        float acc = fc3b[e * 64 + t];
        const float* w = fc3w + (size_t)e * 128 * 64;
        #pragma unroll 8
        for (int c = 0; c < 128; ++c) acc += h2[c] * w[c * 64 + t];
        out[(size_t)(n * 2 + e) * 64 + t] = 1.f / (1.f + expf(-acc));
    }
}

// ---------------- launch ----------------
extern "C" void kernel_launch(void* const* d_in, const int* in_sizes, int n_in,
                              void* d_out, int out_size, void* d_ws, size_t ws_size,
                              hipStream_t stream) {
    const int*   xd1    = (const int*)  d_in[0];
    const int*   xd2    = (const int*)  d_in[1];
    const int*   xd3    = (const int*)  d_in[2];
    const int*   xr1    = (const int*)  d_in[3];
    const int*   xr2    = (const int*)  d_in[4];
    const int*   xr3    = (const int*)  d_in[5];
    const int*   xr4    = (const int*)  d_in[6];
    const float* x_demo = (const float*)d_in[7];
    const float* W_demo = (const float*)d_in[8];
    const float* b_demo = (const float*)d_in[9];
    const float* Ed1    = (const float*)d_in[10];
    const float* Ed2    = (const float*)d_in[11];
    const float* Ed3    = (const float*)d_in[12];
    const float* Er1    = (const float*)d_in[13];
    const float* Er2    = (const float*)d_in[14];
    const float* Er3    = (const float*)d_in[15];
    const float* Er4    = (const float*)d_in[16];
    const float* We_dx  = (const float*)d_in[17];
    const float* be_dx  = (const float*)d_in[18];
    const float* We_rx  = (const float*)d_in[19];
    const float* be_rx  = (const float*)d_in[20];
    const float* Wev_dx = (const float*)d_in[21];
    const float* bev_dx = (const float*)d_in[22];
    const float* Wev_rx = (const float*)d_in[23];
    const float* bev_rx = (const float*)d_in[24];
    const float* Wcv    = (const float*)d_in[25];
    const float* bcv    = (const float*)d_in[26];
    const float* enc_w1 = (const float*)d_in[27];
    const float* enc_b1 = (const float*)d_in[28];
    const float* qkv_w  = (const float*)d_in[29];
    const float* qkv_b  = (const float*)d_in[30];
    const float* ow     = (const float*)d_in[31];
    const float* ob     = (const float*)d_in[32];
    const float* ln1s   = (const float*)d_in[33];
    const float* ln1b   = (const float*)d_in[34];
    const float* ff1w   = (const float*)d_in[35];
    const float* ff1b   = (const float*)d_in[36];
    const float* ff2w   = (const float*)d_in[37];
    const float* ff2b   = (const float*)d_in[38];
    const float* ln2s   = (const float*)d_in[39];
    const float* ln2b   = (const float*)d_in[40];
    const float* enc_w2 = (const float*)d_in[41];
    const float* enc_b2 = (const float*)d_in[42];
    const float* mlp_w  = (const float*)d_in[43];
    const float* mlp_b  = (const float*)d_in[44];
    const float* mlp2_w = (const float*)d_in[45];
    const float* mlp2_b = (const float*)d_in[46];
    const float* fc1w   = (const float*)d_in[47];
    const float* fc1b   = (const float*)d_in[48];
    const float* fc2w   = (const float*)d_in[49];
    const float* fc2b   = (const float*)d_in[50];
    const float* fc3w   = (const float*)d_in[51];
    const float* fc3b   = (const float*)d_in[52];

    float* ws   = (float*)d_ws;
    float* pe   = ws;                      // 1280
    float* ccv  = pe   + 1280;             // 163840
    float* A0   = ccv  + 163840;           // 245760
    float* xbuf = A0   + 245760;           // 327680
    float* qkv  = xbuf + 327680;           // 983040
    float* attn = qkv  + 983040;           // 327680
    float* proj = attn + 327680;           // 327680
    float* ff1  = proj + 327680;           // 2621440
    float* enc  = ff1  + 2621440;          // 163840
    // total ~5.2M floats (~21 MB)

    pe_kernel<<<VIS, DT, 0, stream>>>(pe);
    gram_kernel<<<NV, 256, 0, stream>>>(xd1, xd2, xd3, xr1, xr2, xr3, xr4,
                                        Ed1, Ed2, Ed3, Er1, Er2, Er3, Er4,
                                        We_dx, be_dx, We_rx, be_rx,
                                        Wev_dx, bev_dx, Wev_rx, bev_rx, ccv);
    build_x0<<<NV, 192, 0, stream>>>(x_demo, W_demo, b_demo, ccv, A0);
    gemm_k<<<dim3(DT / 64, NV / 64), 256, 0, stream>>>(A0, enc_w1, enc_b1, pe, xbuf,
                                                       NV, DT, 192, 0);
    for (int i = 0; i < 4; ++i) {
        gemm_k<<<dim3(768 / 64, NV / 64), 256, 0, stream>>>(
            xbuf, qkv_w + (size_t)i * DT * 768, qkv_b + i * 768, nullptr, qkv,
            NV, 768, DT, 0);
        attn_kernel<<<N_PAT, 256, 0, stream>>>(qkv, attn);
        gemm_k<<<dim3(DT / 64, NV / 64), 256, 0, stream>>>(
            attn, ow + (size_t)i * DT * DT, ob + i * DT, nullptr, proj,
            NV, DT, DT, 0);
        ln_kernel<<<NV, 256, 0, stream>>>(xbuf, proj, ln1s + i * DT, ln1b + i * DT, xbuf);
        gemm_k<<<dim3(DFF / 64, NV / 64), 256, 0, stream>>>(
            xbuf, ff1w + (size_t)i * DT * DFF, ff1b + i * DFF, nullptr, ff1,
            NV, DFF, DT, 1);
        gemm_k<<<dim3(DT / 64, NV / 64), 256, 0, stream>>>(
            ff1, ff2w + (size_t)i * DFF * DT, ff2b + i * DT, nullptr, proj,
            NV, DT, DFF, 0);
        ln_kernel<<<NV, 256, 0, stream>>>(xbuf, proj, ln2s + i * DT, ln2b + i * DT, xbuf);
    }
    gemm_k<<<dim3(REP / 64, NV / 64), 256, 0, stream>>>(xbuf, enc_w2, enc_b2, nullptr, enc,
                                                        NV, REP, DT, 0);

    float* civ_out = (float*)d_out + 32768;          // after out [256,2,64]
    float* ph_out  = (float*)d_out + 65536;          // after civ [256,128]
    vc_ph_kernel<<<N_PAT, 128, 0, stream>>>(enc, Wcv, bcv, mlp_w, mlp_b, mlp2_w, mlp2_b,
                                            civ_out, ph_out);
    heads_kernel<<<N_PAT * 2, 256, 0, stream>>>(civ_out, fc1w, fc1b, fc2w, fc2b, fc3w, fc3b,
                                                (float*)d_out);
}

// Round 5
// 677.264 us; speedup vs baseline: 1.5897x; 1.5897x over previous
//
#include <hip/hip_runtime.h>
#include <hip/hip_bf16.h>
#include <math.h>

#define N_PAT 256
#define VIS   5
#define NV    (N_PAT*VIS)   // 1280 rows
#define DD    48            // codes per visit per modality
#define CD    128           // code dim C
#define DT    256
#define NHD   8
#define HD    32
#define DFF   2048
#define REP   128

#define GF_BIAS 1
#define GF_RELU 2
#define GF_PE   4

// ---------------- positional encoding (5 x 256) ----------------
__global__ void pe_kernel(float* __restrict__ pe) {
    int pos = blockIdx.x, c = threadIdx.x;
    int j = c >> 1;
    float ang = (float)pos / powf(10000.f, (2.f * (float)j) / 256.f);
    pe[pos * DT + c] = (c & 1) ? cosf(ang) : sinf(ang);
}

// ---------------- GRAM: code-level + visit-level attention ----------------
__global__ __launch_bounds__(256) void gram_kernel(
    const int* __restrict__ xd1, const int* __restrict__ xd2, const int* __restrict__ xd3,
    const int* __restrict__ xr1, const int* __restrict__ xr2, const int* __restrict__ xr3,
    const int* __restrict__ xr4,
    const float* __restrict__ Ed1, const float* __restrict__ Ed2, const float* __restrict__ Ed3,
    const float* __restrict__ Er1, const float* __restrict__ Er2, const float* __restrict__ Er3,
    const float* __restrict__ Er4,
    const float* __restrict__ We_dx, const float* __restrict__ be_dx,
    const float* __restrict__ We_rx, const float* __restrict__ be_rx,
    const float* __restrict__ Wev_dx, const float* __restrict__ bev_dx,
    const float* __restrict__ Wev_rx, const float* __restrict__ bev_rx,
    float* __restrict__ ccv)
{
    __shared__ float ctx[96][128];
    __shared__ float ev[96];
    const int nv   = blockIdx.x;
    const int tid  = threadIdx.x;
    const int wave = tid >> 6, lane = tid & 63;
    const int base = nv * DD;

    for (int d = wave; d < DD; d += 4) {
        int i1 = xd1[base + d], i2 = xd2[base + d], i3 = xd3[base + d];
        float2 e1 = *(const float2*)(Ed1 + (size_t)i1 * CD + lane * 2);
        float2 e2 = *(const float2*)(Ed2 + (size_t)i2 * CD + lane * 2);
        float2 e3 = *(const float2*)(Ed3 + (size_t)i3 * CD + lane * 2);
        float2 wl = *(const float2*)(We_dx + lane * 2);
        float2 wh = *(const float2*)(We_dx + CD + lane * 2);
        float p0 = e3.x * wl.x + e3.y * wl.y;
        float p1 = e1.x * wh.x + e1.y * wh.y;
        float p2 = e2.x * wh.x + e2.y * wh.y;
        float p3 = e3.x * wh.x + e3.y * wh.y;
        #pragma unroll
        for (int off = 32; off; off >>= 1) {
            p0 += __shfl_xor(p0, off, 64);
            p1 += __shfl_xor(p1, off, 64);
            p2 += __shfl_xor(p2, off, 64);
            p3 += __shfl_xor(p3, off, 64);
        }
        float be = be_dx[0];
        float s1 = fmaxf(p0 + p1 + be, 0.f);
        float s2 = fmaxf(p0 + p2 + be, 0.f);
        float s3 = fmaxf(p0 + p3 + be, 0.f);
        float a1, a2, a3;
        if (i1 != 0) {
            float mx = fmaxf(s1, fmaxf(s2, s3));
            a1 = expf(s1 - mx); a2 = expf(s2 - mx); a3 = expf(s3 - mx);
        } else {
            a1 = a2 = a3 = 1.f;
        }
        float inv = 1.f / (a1 + a2 + a3);
        a1 *= inv; a2 *= inv; a3 *= inv;
        float cx = a1 * e1.x + a2 * e2.x + a3 * e3.x;
        float cy = a1 * e1.y + a2 * e2.y + a3 * e3.y;
        ctx[d][lane * 2]     = cx;
        ctx[d][lane * 2 + 1] = cy;
        float2 wv = *(const float2*)(Wev_dx + lane * 2);
        float pv = cx * wv.x + cy * wv.y;
        #pragma unroll
        for (int off = 32; off; off >>= 1) pv += __shfl_xor(pv, off, 64);
        if (lane == 0) ev[d] = (i1 != 0) ? (pv + bev_dx[0]) : -1e20f;
    }

    for (int d = wave; d < DD; d += 4) {
        int i1 = xr1[base + d], i2 = xr2[base + d], i3 = xr3[base + d], i4 = xr4[base + d];
        float2 e1 = *(const float2*)(Er1 + (size_t)i1 * CD + lane * 2);
        float2 e2 = *(const float2*)(Er2 + (size_t)i2 * CD + lane * 2);
        float2 e3 = *(const float2*)(Er3 + (size_t)i3 * CD + lane * 2);
        float2 e4 = *(const float2*)(Er4 + (size_t)i4 * CD + lane * 2);
        float2 wl = *(const float2*)(We_rx + lane * 2);
        float2 wh = *(const float2*)(We_rx + CD + lane * 2);
        float p0 = e4.x * wl.x + e4.y * wl.y;
        float p1 = e1.x * wh.x + e1.y * wh.y;
        float p2 = e2.x * wh.x + e2.y * wh.y;
        float p3 = e3.x * wh.x + e3.y * wh.y;
        float p4 = e4.x * wh.x + e4.y * wh.y;
        #pragma unroll
        for (int off = 32; off; off >>= 1) {
            p0 += __shfl_xor(p0, off, 64);
            p1 += __shfl_xor(p1, off, 64);
            p2 += __shfl_xor(p2, off, 64);
            p3 += __shfl_xor(p3, off, 64);
            p4 += __shfl_xor(p4, off, 64);
        }
        float be = be_rx[0];
        float s1 = fmaxf(p0 + p1 + be, 0.f);
        float s2 = fmaxf(p0 + p2 + be, 0.f);
        float s3 = fmaxf(p0 + p3 + be, 0.f);
        float s4 = fmaxf(p0 + p4 + be, 0.f);
        float a1, a2, a3, a4;
        if (i1 != 0) {
            float mx = fmaxf(fmaxf(s1, s2), fmaxf(s3, s4));
            a1 = expf(s1 - mx); a2 = expf(s2 - mx); a3 = expf(s3 - mx); a4 = expf(s4 - mx);
        } else {
            a1 = a2 = a3 = a4 = 1.f;
        }
        float inv = 1.f / (a1 + a2 + a3 + a4);
        a1 *= inv; a2 *= inv; a3 *= inv; a4 *= inv;
        float cx = a1 * e1.x + a2 * e2.x + a3 * e3.x + a4 * e4.x;
        float cy = a1 * e1.y + a2 * e2.y + a3 * e3.y + a4 * e4.y;
        ctx[DD + d][lane * 2]     = cx;
        ctx[DD + d][lane * 2 + 1] = cy;
        float2 wv = *(const float2*)(Wev_rx + lane * 2);
        float pv = cx * wv.x + cy * wv.y;
        #pragma unroll
        for (int off = 32; off; off >>= 1) pv += __shfl_xor(pv, off, 64);
        if (lane == 0) ev[DD + d] = (i1 != 0) ? (pv + bev_rx[0]) : -1e20f;
    }
    __syncthreads();

    if (wave == 0) {
        float a = ev[lane];
        float b = (lane < 32) ? ev[64 + lane] : -3.0e38f;
        float mx = fmaxf(a, b);
        #pragma unroll
        for (int off = 32; off; off >>= 1) mx = fmaxf(mx, __shfl_xor(mx, off, 64));
        float ea = expf(a - mx);
        float eb = (lane < 32) ? expf(b - mx) : 0.f;
        float s = ea + eb;
        #pragma unroll
        for (int off = 32; off; off >>= 1) s += __shfl_xor(s, off, 64);
        float inv = 1.f / s;
        ev[lane] = ea * inv;
        if (lane < 32) ev[64 + lane] = eb * inv;
    }
    __syncthreads();

    if (tid < CD) {
        float acc = 0.f;
        #pragma unroll 8
        for (int m = 0; m < 96; ++m) acc += ev[m] * ctx[m][tid];
        ccv[(size_t)nv * CD + tid] = acc;
    }
}

// ---------------- build x0 = [relu(x_demo@W_demo+b), ccv] : [1280,192] ----------------
__global__ __launch_bounds__(192) void build_x0(
    const float* __restrict__ x_demo, const float* __restrict__ W_demo,
    const float* __restrict__ b_demo, const float* __restrict__ ccv,
    float* __restrict__ A0)
{
    int row = blockIdx.x, j = threadIdx.x;
    if (j < 64) {
        float acc = b_demo[j];
        #pragma unroll
        for (int f = 0; f < 32; ++f) acc += x_demo[row * 32 + f] * W_demo[f * 64 + j];
        A0[row * 192 + j] = fmaxf(acc, 0.f);
    } else {
        A0[row * 192 + j] = ccv[row * CD + (j - 64)];
    }
}

// ---------------- tiled f32 GEMM with optional split-K ----------------
// A [M,K], B [K,N] row-major. BM=BN=64, BK=16, 256 thr, 4x4 microtile.
// gridDim.z > 1: each z handles kchunk of K, writes raw partial to C + z*M*N.
__global__ __launch_bounds__(256) void gemm_k(
    const float* __restrict__ A, const float* __restrict__ B,
    const float* __restrict__ bias, const float* __restrict__ pe,
    float* __restrict__ C, int M, int N, int K, int flags, int kchunk)
{
    __shared__ float As[16][68];   // [k][m]; pad 68: rows 16B-aligned, 2-way write alias (free)
    __shared__ float Bs[16][64];   // [k][n]
    const int bm = blockIdx.y * 64, bn = blockIdx.x * 64;
    const int tid = threadIdx.x;
    const int tx = tid & 15, ty = tid >> 4;
    const int kbeg = blockIdx.z * kchunk;
    const int kend = kbeg + kchunk;
    const int ar  = tid >> 2, akc = (tid & 3) * 4;   // A: row, k-offset (float4)
    const int bbr = tid >> 4, bbc = (tid & 15) * 4;  // B: k-row, col (float4)
    float acc[4][4] = {{0.f}};

    for (int k0 = kbeg; k0 < kend; k0 += 16) {
        float4 va = *(const float4*)(A + (size_t)(bm + ar) * K + k0 + akc);
        float4 vb = *(const float4*)(B + (size_t)(k0 + bbr) * N + bn + bbc);
        As[akc + 0][ar] = va.x;
        As[akc + 1][ar] = va.y;
        As[akc + 2][ar] = va.z;
        As[akc + 3][ar] = va.w;
        *(float4*)&Bs[bbr][bbc] = vb;
        __syncthreads();
        #pragma unroll
        for (int kk = 0; kk < 16; ++kk) {
            float4 a = *(const float4*)&As[kk][ty * 4];
            float4 b = *(const float4*)&Bs[kk][tx * 4];
            acc[0][0] += a.x * b.x; acc[0][1] += a.x * b.y; acc[0][2] += a.x * b.z; acc[0][3] += a.x * b.w;
            acc[1][0] += a.y * b.x; acc[1][1] += a.y * b.y; acc[1][2] += a.y * b.z; acc[1][3] += a.y * b.w;
            acc[2][0] += a.z * b.x; acc[2][1] += a.z * b.y; acc[2][2] += a.z * b.z; acc[2][3] += a.z * b.w;
            acc[3][0] += a.w * b.x; acc[3][1] += a.w * b.y; acc[3][2] += a.w * b.z; acc[3][3] += a.w * b.w;
        }
        __syncthreads();
    }

    if (gridDim.z == 1) {
        #pragma unroll
        for (int i = 0; i < 4; ++i) {
            int row = bm + ty * 4 + i;
            int col0 = bn + tx * 4;
            float4 v = *(float4*)&acc[i][0];
            if (flags & GF_BIAS) {
                const float4 bz = *(const float4*)(bias + col0);
                v.x += bz.x; v.y += bz.y; v.z += bz.z; v.w += bz.w;
            }
            if (flags & GF_PE) {
                const float4 pz = *(const float4*)(pe + (row % VIS) * N + col0);
                v.x += pz.x; v.y += pz.y; v.z += pz.z; v.w += pz.w;
            }
            if (flags & GF_RELU) {
                v.x = fmaxf(v.x, 0.f); v.y = fmaxf(v.y, 0.f);
                v.z = fmaxf(v.z, 0.f); v.w = fmaxf(v.w, 0.f);
            }
            *(float4*)(C + (size_t)row * N + col0) = v;
        }
    } else {
        float* Cp = C + (size_t)blockIdx.z * M * N;
        #pragma unroll
        for (int i = 0; i < 4; ++i) {
            int row = bm + ty * 4 + i;
            *(float4*)(Cp + (size_t)row * N + bn + tx * 4) = *(float4*)&acc[i][0];
        }
    }
}

// ---------------- split-K reduce + bias (+pe) (+residual) (+LayerNorm) (+relu) ----------------
// grid = M rows, block = N threads (N = 128 or 256)
__global__ void reduce_kernel(
    const float* __restrict__ part, int S, int MN,
    const float* __restrict__ bias, const float* __restrict__ pe,
    const float* __restrict__ resid,
    const float* __restrict__ lns, const float* __restrict__ lnb,
    int relu, int N, float* __restrict__ out)
{
    const int row = blockIdx.x, t = threadIdx.x;
    const size_t idx = (size_t)row * N + t;
    float v = bias[t];
    for (int s = 0; s < S; ++s) v += part[(size_t)s * MN + idx];
    if (pe)    v += pe[(row % VIS) * N + t];
    if (resid) v += resid[idx];
    if (lns) {
        float s1 = v, s2 = v * v;
        #pragma unroll
        for (int off = 32; off; off >>= 1) {
            s1 += __shfl_xor(s1, off, 64);
            s2 += __shfl_xor(s2, off, 64);
        }
        __shared__ float red[2][4];
        const int wave = t >> 6, lane = t & 63, nw = blockDim.x >> 6;
        if (lane == 0) { red[0][wave] = s1; red[1][wave] = s2; }
        __syncthreads();
        s1 = 0.f; s2 = 0.f;
        for (int w = 0; w < nw; ++w) { s1 += red[0][w]; s2 += red[1][w]; }
        float invn = 1.f / (float)N;
        float m    = s1 * invn;
        float var  = s2 * invn - m * m;
        float inv  = 1.f / sqrtf(var + 1e-5f);
        v = (v - m) * inv * lns[t] + lnb[t];
    }
    if (relu) v = fmaxf(v, 0.f);
    out[idx] = v;
}

// ---------------- attention: sums S qkv partials + bias; block per n ----------------
__global__ __launch_bounds__(256) void attn_kernel(
    const float* __restrict__ qkvp, int S, int MN,
    const float* __restrict__ qb, float* __restrict__ out)
{
    const int n = blockIdx.x;
    const int tid = threadIdx.x;
    const int h = tid >> 5, t = tid & 31;
    const int ch = h * HD + t;
    float q[VIS], k[VIS], v[VIS];
    #pragma unroll
    for (int j = 0; j < VIS; ++j) {
        size_t idx = (size_t)(n * VIS + j) * 768 + ch;
        float qq = qb[ch], kk = qb[256 + ch], vv = qb[512 + ch];
        for (int s = 0; s < S; ++s) {
            const float* p = qkvp + (size_t)s * MN + idx;
            qq += p[0]; kk += p[256]; vv += p[512];
        }
        q[j] = qq; k[j] = kk; v[j] = vv;
    }
    const float scale = 0.1767766952966369f;  // 1/sqrt(32)
    float sm[VIS][VIS];
    #pragma unroll
    for (int qi = 0; qi < VIS; ++qi)
        #pragma unroll
        for (int ki = 0; ki < VIS; ++ki) {
            float p = q[qi] * k[ki];
            #pragma unroll
            for (int off = 16; off; off >>= 1) p += __shfl_xor(p, off, 32);
            sm[qi][ki] = p * scale;
        }
    #pragma unroll
    for (int qi = 0; qi < VIS; ++qi) {
        float mx = sm[qi][0];
        #pragma unroll
        for (int ki = 1; ki < VIS; ++ki) mx = fmaxf(mx, sm[qi][ki]);
        float e[VIS], sum = 0.f;
        #pragma unroll
        for (int ki = 0; ki < VIS; ++ki) { e[ki] = expf(sm[qi][ki] - mx); sum += e[ki]; }
        float inv = 1.f / sum;
        float acc = 0.f;
        #pragma unroll
        for (int ki = 0; ki < VIS; ++ki) acc += e[ki] * inv * v[ki];
        out[(size_t)(n * VIS + qi) * DT + ch] = acc;
    }
}

// ---------------- visit compression + ph MLP ----------------
__global__ __launch_bounds__(128) void vc_ph_kernel(
    const float* __restrict__ enc, const float* __restrict__ Wcv, const float* __restrict__ bcv,
    const float* __restrict__ mlp_w, const float* __restrict__ mlp_b,
    const float* __restrict__ mlp2_w, const float* __restrict__ mlp2_b,
    float* __restrict__ civ_out, float* __restrict__ ph_out)
{
    const int n = blockIdx.x, t = threadIdx.x;
    const int wave = t >> 6, lane = t & 63;
    float e[VIS];
    #pragma unroll
    for (int v = 0; v < VIS; ++v) e[v] = enc[(size_t)(n * VIS + v) * REP + t];
    float w = Wcv[t];
    __shared__ float part[VIS][2];
    #pragma unroll
    for (int v = 0; v < VIS; ++v) {
        float pv = e[v] * w;
        #pragma unroll
        for (int off = 32; off; off >>= 1) pv += __shfl_xor(pv, off, 64);
        if (lane == 0) part[v][wave] = pv;
    }
    __syncthreads();
    float b0 = bcv[0];
    float sc[VIS], mx = -3e38f;
    #pragma unroll
    for (int v = 0; v < VIS; ++v) { sc[v] = part[v][0] + part[v][1] + b0; mx = fmaxf(mx, sc[v]); }
    float sum = 0.f;
    #pragma unroll
    for (int v = 0; v < VIS; ++v) { sc[v] = expf(sc[v] - mx); sum += sc[v]; }
    float inv = 1.f / sum;
    float civ = 0.f;
    #pragma unroll
    for (int v = 0; v < VIS; ++v) civ += sc[v] * inv * e[v];
    civ_out[(size_t)n * REP + t] = civ;

    __shared__ float civ_s[REP];
    __shared__ float h1_s[64];
    civ_s[t] = civ;
    __syncthreads();
    if (t < 64) {
        float acc = mlp_b[t];
        #pragma unroll 8
        for (int c = 0; c < REP; ++c) acc += civ_s[c] * mlp_w[c * 64 + t];
        h1_s[t] = fmaxf(acc, 0.f);
    }
    __syncthreads();
    if (t < 64) {
        float acc = mlp2_b[t];
        #pragma unroll 8
        for (int j = 0; j < 64; ++j) acc += h1_s[j] * mlp2_w[j * 64 + t];
        ph_out[(size_t)n * 64 + t] = acc;
    }
}

// ---------------- per-event FC heads ----------------
__global__ __launch_bounds__(256) void heads_kernel(
    const float* __restrict__ civ,
    const float* __restrict__ fc1w, const float* __restrict__ fc1b,
    const float* __restrict__ fc2w, const float* __restrict__ fc2b,
    const float* __restrict__ fc3w, const float* __restrict__ fc3b,
    float* __restrict__ out)
{
    const int n = blockIdx.x >> 1, e = blockIdx.x & 1;
    const int t = threadIdx.x;
    __shared__ float civ_s[REP], h1[256], h2[128];
    if (t < REP) civ_s[t] = civ[(size_t)n * REP + t];
    __syncthreads();
    {
        float acc = fc1b[e * 256 + t];
        const float* w = fc1w + (size_t)e * REP * 256;
        #pragma unroll 8
        for (int c = 0; c < REP; ++c) acc += civ_s[c] * w[c * 256 + t];
        h1[t] = fmaxf(acc, 0.f);
    }
    __syncthreads();
    if (t < 128) {
        float acc = fc2b[e * 128 + t];
        const float* w = fc2w + (size_t)e * 256 * 128;
        #pragma unroll 8
        for (int c = 0; c < 256; ++c) acc += h1[c] * w[c * 128 + t];
        h2[t] = fmaxf(acc, 0.f);
    }
    __syncthreads();
    if (t < 64) {
        float acc = fc3b[e * 64 + t];
        const float* w = fc3w + (size_t)e * 128 * 64;
        #pragma unroll 8
        for (int c = 0; c < 128; ++c) acc += h2[c] * w[c * 64 + t];
        out[(size_t)(n * 2 + e) * 64 + t] = 1.f / (1.f + expf(-acc));
    }
}

// ---------------- launch ----------------
extern "C" void kernel_launch(void* const* d_in, const int* in_sizes, int n_in,
                              void* d_out, int out_size, void* d_ws, size_t ws_size,
                              hipStream_t stream) {
    const int*   xd1    = (const int*)  d_in[0];
    const int*   xd2    = (const int*)  d_in[1];
    const int*   xd3    = (const int*)  d_in[2];
    const int*   xr1    = (const int*)  d_in[3];
    const int*   xr2    = (const int*)  d_in[4];
    const int*   xr3    = (const int*)  d_in[5];
    const int*   xr4    = (const int*)  d_in[6];
    const float* x_demo = (const float*)d_in[7];
    const float* W_demo = (const float*)d_in[8];
    const float* b_demo = (const float*)d_in[9];
    const float* Ed1    = (const float*)d_in[10];
    const float* Ed2    = (const float*)d_in[11];
    const float* Ed3    = (const float*)d_in[12];
    const float* Er1    = (const float*)d_in[13];
    const float* Er2    = (const float*)d_in[14];
    const float* Er3    = (const float*)d_in[15];
    const float* Er4    = (const float*)d_in[16];
    const float* We_dx  = (const float*)d_in[17];
    const float* be_dx  = (const float*)d_in[18];
    const float* We_rx  = (const float*)d_in[19];
    const float* be_rx  = (const float*)d_in[20];
    const float* Wev_dx = (const float*)d_in[21];
    const float* bev_dx = (const float*)d_in[22];
    const float* Wev_rx = (const float*)d_in[23];
    const float* bev_rx = (const float*)d_in[24];
    const float* Wcv    = (const float*)d_in[25];
    const float* bcv    = (const float*)d_in[26];
    const float* enc_w1 = (const float*)d_in[27];
    const float* enc_b1 = (const float*)d_in[28];
    const float* qkv_w  = (const float*)d_in[29];
    const float* qkv_b  = (const float*)d_in[30];
    const float* ow     = (const float*)d_in[31];
    const float* ob     = (const float*)d_in[32];
    const float* ln1s   = (const float*)d_in[33];
    const float* ln1b   = (const float*)d_in[34];
    const float* ff1w   = (const float*)d_in[35];
    const float* ff1b   = (const float*)d_in[36];
    const float* ff2w   = (const float*)d_in[37];
    const float* ff2b   = (const float*)d_in[38];
    const float* ln2s   = (const float*)d_in[39];
    const float* ln2b   = (const float*)d_in[40];
    const float* enc_w2 = (const float*)d_in[41];
    const float* enc_b2 = (const float*)d_in[42];
    const float* mlp_w  = (const float*)d_in[43];
    const float* mlp_b  = (const float*)d_in[44];
    const float* mlp2_w = (const float*)d_in[45];
    const float* mlp2_b = (const float*)d_in[46];
    const float* fc1w   = (const float*)d_in[47];
    const float* fc1b   = (const float*)d_in[48];
    const float* fc2w   = (const float*)d_in[49];
    const float* fc2b   = (const float*)d_in[50];
    const float* fc3w   = (const float*)d_in[51];
    const float* fc3b   = (const float*)d_in[52];

    // workspace layout (floats): total 5,076,480 (~20.3 MB) -- below proven-safe r1 footprint
    float* ws   = (float*)d_ws;
    float* pe   = ws;                      // 1,280
    float* ccv  = pe   + 1280;             // 163,840
    float* xbuf = ccv  + 163840;           // 327,680
    float* attn = xbuf + 327680;           // 327,680
    float* enc  = attn + 327680;           // 163,840
    float* buf1 = enc  + 163840;           // 2,621,440: qkv partials (z=2) / ff1 out
    float* buf2 = buf1 + 2621440;          // 1,310,720: proj z=4 / ff2 z=4 / enc z=4 partials
    float* A0   = buf2;                    // alias: A0 [1280,192] dead before buf2 first used

    pe_kernel<<<VIS, DT, 0, stream>>>(pe);
    gram_kernel<<<NV, 256, 0, stream>>>(xd1, xd2, xd3, xr1, xr2, xr3, xr4,
                                        Ed1, Ed2, Ed3, Er1, Er2, Er3, Er4,
                                        We_dx, be_dx, We_rx, be_rx,
                                        Wev_dx, bev_dx, Wev_rx, bev_rx, ccv);
    build_x0<<<NV, 192, 0, stream>>>(x_demo, W_demo, b_demo, ccv, A0);

    // x = A0 @ enc_w1 + b + pe    [1280,256], K=192, z=1
    gemm_k<<<dim3(4, 20, 1), 256, 0, stream>>>(A0, enc_w1, enc_b1, pe, xbuf,
                                               NV, DT, 192, GF_BIAS | GF_PE, 192);

    for (int i = 0; i < 4; ++i) {
        // qkv: [1280,768], K=256, z=2 (kchunk 128) -> 480 blocks; bias folded into attn
        gemm_k<<<dim3(12, 20, 2), 256, 0, stream>>>(
            xbuf, qkv_w + (size_t)i * DT * 768, nullptr, nullptr, buf1,
            NV, 768, DT, 0, 128);
        attn_kernel<<<N_PAT, 256, 0, stream>>>(buf1, 2, NV * 768, qkv_b + i * 768, attn);
        // proj: [1280,256], K=256, z=4 (kchunk 64) -> 320 blocks
        gemm_k<<<dim3(4, 20, 4), 256, 0, stream>>>(
            attn, ow + (size_t)i * DT * DT, nullptr, nullptr, buf2,
            NV, DT, DT, 0, 64);
        // sum 4 partials + ob + residual(xbuf) -> LN1 -> xbuf
        reduce_kernel<<<NV, DT, 0, stream>>>(buf2, 4, NV * DT, ob + i * DT, nullptr,
                                             xbuf, ln1s + i * DT, ln1b + i * DT, 0, DT, xbuf);
        // ff1: [1280,2048], K=256, z=1 -> 640 blocks, bias+relu in epilogue
        gemm_k<<<dim3(32, 20, 1), 256, 0, stream>>>(
            xbuf, ff1w + (size_t)i * DT * DFF, ff1b + i * DFF, nullptr, buf1,
            NV, DFF, DT, GF_BIAS | GF_RELU, DT);
        // ff2: [1280,256], K=2048, z=4 (kchunk 512) -> 320 blocks
        gemm_k<<<dim3(4, 20, 4), 256, 0, stream>>>(
            buf1, ff2w + (size_t)i * DFF * DT, nullptr, nullptr, buf2,
            NV, DT, DFF, 0, 512);
        // sum 4 partials + ff2b + residual(xbuf) -> LN2 -> xbuf
        reduce_kernel<<<NV, DT, 0, stream>>>(buf2, 4, NV * DT, ff2b + i * DT, nullptr,
                                             xbuf, ln2s + i * DT, ln2b + i * DT, 0, DT, xbuf);
    }

    // enc: [1280,128], K=256, z=4 (kchunk 64) -> 160 blocks
    gemm_k<<<dim3(2, 20, 4), 256, 0, stream>>>(xbuf, enc_w2, nullptr, nullptr, buf2,
                                               NV, REP, DT, 0, 64);
    reduce_kernel<<<NV, REP, 0, stream>>>(buf2, 4, NV * REP, enc_b2, nullptr,
                                          nullptr, nullptr, nullptr, 0, REP, enc);

    float* civ_out = (float*)d_out + 32768;          // after out [256,2,64]
    float* ph_out  = (float*)d_out + 65536;          // after civ [256,128]
    vc_ph_kernel<<<N_PAT, 128, 0, stream>>>(enc, Wcv, bcv, mlp_w, mlp_b, mlp2_w, mlp2_b,
                                            civ_out, ph_out);
    heads_kernel<<<N_PAT * 2, 256, 0, stream>>>(civ_out, fc1w, fc1b, fc2w, fc2b, fc3w, fc3b,
                                                (float*)d_out);
}

// Round 6
// 658.344 us; speedup vs baseline: 1.6354x; 1.0287x over previous
//
#include <hip/hip_runtime.h>
#include <hip/hip_bf16.h>
#include <math.h>

#define N_PAT 256
#define VIS   5
#define NV    (N_PAT*VIS)   // 1280 rows
#define DD    48            // codes per visit per modality
#define CD    128           // code dim C
#define DT    256
#define NHD   8
#define HD    32
#define DFF   2048
#define REP   128

#define GF_BIAS 1
#define GF_RELU 2
#define GF_PE   4

// ---------------- positional encoding (5 x 256) ----------------
__global__ void pe_kernel(float* __restrict__ pe) {
    int pos = blockIdx.x, c = threadIdx.x;
    int j = c >> 1;
    float ang = (float)pos / powf(10000.f, (2.f * (float)j) / 256.f);
    pe[pos * DT + c] = (c & 1) ? cosf(ang) : sinf(ang);
}

// ---------------- per-table row projections: hi/lo/wev dots ----------------
// out[row*4+0] = E[row].We_hi, +1 = E[row].We_lo, +2 = E[row].Wev
// wave per row, lane owns 2 channels
__global__ __launch_bounds__(256) void proj_kernel(
    const float* __restrict__ E, const float* __restrict__ W_lo,
    const float* __restrict__ W_hi, const float* __restrict__ Wev,
    int nrows, float* __restrict__ out)
{
    const int row = blockIdx.x * 4 + (threadIdx.x >> 6);
    const int lane = threadIdx.x & 63;
    if (row >= nrows) return;
    float2 e   = *(const float2*)(E + (size_t)row * CD + lane * 2);
    float2 whi = *(const float2*)(W_hi + lane * 2);
    float2 wlo = *(const float2*)(W_lo + lane * 2);
    float2 wev = *(const float2*)(Wev + lane * 2);
    float ph = e.x * whi.x + e.y * whi.y;
    float pl = e.x * wlo.x + e.y * wlo.y;
    float pw = e.x * wev.x + e.y * wev.y;
    #pragma unroll
    for (int off = 32; off; off >>= 1) {
        ph += __shfl_xor(ph, off, 64);
        pl += __shfl_xor(pl, off, 64);
        pw += __shfl_xor(pw, off, 64);
    }
    if (lane == 0) {
        out[(size_t)row * 4 + 0] = ph;
        out[(size_t)row * 4 + 1] = pl;
        out[(size_t)row * 4 + 2] = pw;
        out[(size_t)row * 4 + 3] = 0.f;
    }
}

// ---------------- GRAM via precomputed projections ----------------
// Phase A: scalar per-code softmax + visit logits (no shuffles, no ctx array).
// Phase B: ccv[c] = sum over (code,level) of weight * emb[c].
__global__ __launch_bounds__(256) void gram_kernel(
    const int* __restrict__ xd1, const int* __restrict__ xd2, const int* __restrict__ xd3,
    const int* __restrict__ xr1, const int* __restrict__ xr2, const int* __restrict__ xr3,
    const int* __restrict__ xr4,
    const float* __restrict__ Ed1, const float* __restrict__ Ed2, const float* __restrict__ Ed3,
    const float* __restrict__ Er1, const float* __restrict__ Er2, const float* __restrict__ Er3,
    const float* __restrict__ Er4,
    const float* __restrict__ pd1, const float* __restrict__ pd2, const float* __restrict__ pd3,
    const float* __restrict__ pr1, const float* __restrict__ pr2, const float* __restrict__ pr3,
    const float* __restrict__ pr4,
    const float* __restrict__ be_dx, const float* __restrict__ be_rx,
    const float* __restrict__ bev_dx, const float* __restrict__ bev_rx,
    float* __restrict__ ccv)
{
    __shared__ float aw[96][4];    // per-code level weights (later scaled by att_v)
    __shared__ float ev[96];       // visit logits -> weights
    __shared__ int   sidx[96][4];  // gathered indices
    __shared__ float part[4][128]; // per-wave partial ccv
    const int nv   = blockIdx.x;
    const int tid  = threadIdx.x;
    const int wave = tid >> 6, lane = tid & 63;
    const int base = nv * DD;

    // ---- phase A: wave 0 lanes 0-47 do dx, wave 1 lanes 0-47 do rx ----
    if (tid < 48) {
        const int d = tid;
        const int i1 = xd1[base + d], i2 = xd2[base + d], i3 = xd3[base + d];
        sidx[d][0] = i1; sidx[d][1] = i2; sidx[d][2] = i3;
        float4 q1 = *(const float4*)(pd1 + (size_t)i1 * 4);
        float4 q2 = *(const float4*)(pd2 + (size_t)i2 * 4);
        float4 q3 = *(const float4*)(pd3 + (size_t)i3 * 4);
        const float be = be_dx[0];
        const float p0 = q3.y;                    // dot(emb3, We_lo)
        float s1 = fmaxf(p0 + q1.x + be, 0.f);
        float s2 = fmaxf(p0 + q2.x + be, 0.f);
        float s3 = fmaxf(p0 + q3.x + be, 0.f);
        float a1, a2, a3;
        if (i1 != 0) {
            float mx = fmaxf(s1, fmaxf(s2, s3));
            a1 = expf(s1 - mx); a2 = expf(s2 - mx); a3 = expf(s3 - mx);
        } else {
            a1 = a2 = a3 = 1.f;
        }
        float inv = 1.f / (a1 + a2 + a3);
        a1 *= inv; a2 *= inv; a3 *= inv;
        aw[d][0] = a1; aw[d][1] = a2; aw[d][2] = a3; aw[d][3] = 0.f;
        ev[d] = (i1 != 0) ? (a1 * q1.z + a2 * q2.z + a3 * q3.z + bev_dx[0]) : -1e20f;
    } else if (tid >= 64 && tid < 112) {
        const int d = tid - 64;
        const int i1 = xr1[base + d], i2 = xr2[base + d], i3 = xr3[base + d], i4 = xr4[base + d];
        const int m = 48 + d;
        sidx[m][0] = i1; sidx[m][1] = i2; sidx[m][2] = i3; sidx[m][3] = i4;
        float4 q1 = *(const float4*)(pr1 + (size_t)i1 * 4);
        float4 q2 = *(const float4*)(pr2 + (size_t)i2 * 4);
        float4 q3 = *(const float4*)(pr3 + (size_t)i3 * 4);
        float4 q4 = *(const float4*)(pr4 + (size_t)i4 * 4);
        const float be = be_rx[0];
        const float p0 = q4.y;                    // dot(emb4, We_lo)
        float s1 = fmaxf(p0 + q1.x + be, 0.f);
        float s2 = fmaxf(p0 + q2.x + be, 0.f);
        float s3 = fmaxf(p0 + q3.x + be, 0.f);
        float s4 = fmaxf(p0 + q4.x + be, 0.f);
        float a1, a2, a3, a4;
        if (i1 != 0) {
            float mx = fmaxf(fmaxf(s1, s2), fmaxf(s3, s4));
            a1 = expf(s1 - mx); a2 = expf(s2 - mx); a3 = expf(s3 - mx); a4 = expf(s4 - mx);
        } else {
            a1 = a2 = a3 = a4 = 1.f;
        }
        float inv = 1.f / (a1 + a2 + a3 + a4);
        aw[m][0] = a1 * inv; aw[m][1] = a2 * inv; aw[m][2] = a3 * inv; aw[m][3] = a4 * inv;
        ev[m] = (i1 != 0) ? ((a1 * q1.z + a2 * q2.z + a3 * q3.z + a4 * q4.z) * inv + bev_rx[0])
                          : -1e20f;
    }
    __syncthreads();

    // ---- visit-level softmax over 96 logits (wave 0) ----
    if (wave == 0) {
        float a = ev[lane];
        float b = (lane < 32) ? ev[64 + lane] : -3.0e38f;
        float mx = fmaxf(a, b);
        #pragma unroll
        for (int off = 32; off; off >>= 1) mx = fmaxf(mx, __shfl_xor(mx, off, 64));
        float ea = expf(a - mx);
        float eb = (lane < 32) ? expf(b - mx) : 0.f;
        float s = ea + eb;
        #pragma unroll
        for (int off = 32; off; off >>= 1) s += __shfl_xor(s, off, 64);
        float inv = 1.f / s;
        ev[lane] = ea * inv;
        if (lane < 32) ev[64 + lane] = eb * inv;
    }
    __syncthreads();

    // ---- fold att_v into per-level weights ----
    if (tid < 96) {
        float av = ev[tid];
        aw[tid][0] *= av; aw[tid][1] *= av; aw[tid][2] *= av; aw[tid][3] *= av;
    }
    __syncthreads();

    // ---- phase B: weighted embedding gather-accumulate (lane owns 2 channels) ----
    float accx = 0.f, accy = 0.f;
    const int co = lane * 2;
    for (int m = wave; m < 96; m += 4) {
        if (m < 48) {
            int i1 = sidx[m][0], i2 = sidx[m][1], i3 = sidx[m][2];
            float2 e1 = *(const float2*)(Ed1 + (size_t)i1 * CD + co);
            float2 e2 = *(const float2*)(Ed2 + (size_t)i2 * CD + co);
            float2 e3 = *(const float2*)(Ed3 + (size_t)i3 * CD + co);
            float w1 = aw[m][0], w2 = aw[m][1], w3 = aw[m][2];
            accx += w1 * e1.x + w2 * e2.x + w3 * e3.x;
            accy += w1 * e1.y + w2 * e2.y + w3 * e3.y;
        } else {
            int i1 = sidx[m][0], i2 = sidx[m][1], i3 = sidx[m][2], i4 = sidx[m][3];
            float2 e1 = *(const float2*)(Er1 + (size_t)i1 * CD + co);
            float2 e2 = *(const float2*)(Er2 + (size_t)i2 * CD + co);
            float2 e3 = *(const float2*)(Er3 + (size_t)i3 * CD + co);
            float2 e4 = *(const float2*)(Er4 + (size_t)i4 * CD + co);
            float w1 = aw[m][0], w2 = aw[m][1], w3 = aw[m][2], w4 = aw[m][3];
            accx += w1 * e1.x + w2 * e2.x + w3 * e3.x + w4 * e4.x;
            accy += w1 * e1.y + w2 * e2.y + w3 * e3.y + w4 * e4.y;
        }
    }
    part[wave][co]     = accx;
    part[wave][co + 1] = accy;
    __syncthreads();
    if (tid < CD) {
        ccv[(size_t)nv * CD + tid] =
            part[0][tid] + part[1][tid] + part[2][tid] + part[3][tid];
    }
}

// ---------------- build x0 = [relu(x_demo@W_demo+b), ccv] : [1280,192] ----------------
__global__ __launch_bounds__(192) void build_x0(
    const float* __restrict__ x_demo, const float* __restrict__ W_demo,
    const float* __restrict__ b_demo, const float* __restrict__ ccv,
    float* __restrict__ A0)
{
    int row = blockIdx.x, j = threadIdx.x;
    if (j < 64) {
        float acc = b_demo[j];
        #pragma unroll
        for (int f = 0; f < 32; ++f) acc += x_demo[row * 32 + f] * W_demo[f * 64 + j];
        A0[row * 192 + j] = fmaxf(acc, 0.f);
    } else {
        A0[row * 192 + j] = ccv[row * CD + (j - 64)];
    }
}

// ---------------- tiled f32 GEMM with optional split-K ----------------
// A [M,K], B [K,N] row-major. BM=BN=64, BK=16, 256 thr, 4x4 microtile.
// gridDim.z > 1: each z handles kchunk of K, writes raw partial to C + z*M*N.
__global__ __launch_bounds__(256) void gemm_k(
    const float* __restrict__ A, const float* __restrict__ B,
    const float* __restrict__ bias, const float* __restrict__ pe,
    float* __restrict__ C, int M, int N, int K, int flags, int kchunk)
{
    __shared__ float As[16][68];   // [k][m]; pad 68: rows 16B-aligned, 2-way write alias (free)
    __shared__ float Bs[16][64];   // [k][n]
    const int bm = blockIdx.y * 64, bn = blockIdx.x * 64;
    const int tid = threadIdx.x;
    const int tx = tid & 15, ty = tid >> 4;
    const int kbeg = blockIdx.z * kchunk;
    const int kend = kbeg + kchunk;
    const int ar  = tid >> 2, akc = (tid & 3) * 4;   // A: row, k-offset (float4)
    const int bbr = tid >> 4, bbc = (tid & 15) * 4;  // B: k-row, col (float4)
    float acc[4][4] = {{0.f}};

    for (int k0 = kbeg; k0 < kend; k0 += 16) {
        float4 va = *(const float4*)(A + (size_t)(bm + ar) * K + k0 + akc);
        float4 vb = *(const float4*)(B + (size_t)(k0 + bbr) * N + bn + bbc);
        As[akc + 0][ar] = va.x;
        As[akc + 1][ar] = va.y;
        As[akc + 2][ar] = va.z;
        As[akc + 3][ar] = va.w;
        *(float4*)&Bs[bbr][bbc] = vb;
        __syncthreads();
        #pragma unroll
        for (int kk = 0; kk < 16; ++kk) {
            float4 a = *(const float4*)&As[kk][ty * 4];
            float4 b = *(const float4*)&Bs[kk][tx * 4];
            acc[0][0] += a.x * b.x; acc[0][1] += a.x * b.y; acc[0][2] += a.x * b.z; acc[0][3] += a.x * b.w;
            acc[1][0] += a.y * b.x; acc[1][1] += a.y * b.y; acc[1][2] += a.y * b.z; acc[1][3] += a.y * b.w;
            acc[2][0] += a.z * b.x; acc[2][1] += a.z * b.y; acc[2][2] += a.z * b.z; acc[2][3] += a.z * b.w;
            acc[3][0] += a.w * b.x; acc[3][1] += a.w * b.y; acc[3][2] += a.w * b.z; acc[3][3] += a.w * b.w;
        }
        __syncthreads();
    }

    if (gridDim.z == 1) {
        #pragma unroll
        for (int i = 0; i < 4; ++i) {
            int row = bm + ty * 4 + i;
            int col0 = bn + tx * 4;
            float4 v = *(float4*)&acc[i][0];
            if (flags & GF_BIAS) {
                const float4 bz = *(const float4*)(bias + col0);
                v.x += bz.x; v.y += bz.y; v.z += bz.z; v.w += bz.w;
            }
            if (flags & GF_PE) {
                const float4 pz = *(const float4*)(pe + (row % VIS) * N + col0);
                v.x += pz.x; v.y += pz.y; v.z += pz.z; v.w += pz.w;
            }
            if (flags & GF_RELU) {
                v.x = fmaxf(v.x, 0.f); v.y = fmaxf(v.y, 0.f);
                v.z = fmaxf(v.z, 0.f); v.w = fmaxf(v.w, 0.f);
            }
            *(float4*)(C + (size_t)row * N + col0) = v;
        }
    } else {
        float* Cp = C + (size_t)blockIdx.z * M * N;
        #pragma unroll
        for (int i = 0; i < 4; ++i) {
            int row = bm + ty * 4 + i;
            *(float4*)(Cp + (size_t)row * N + bn + tx * 4) = *(float4*)&acc[i][0];
        }
    }
}

// ---------------- split-K reduce + bias (+pe) (+residual) (+LayerNorm) (+relu) ----------------
__global__ void reduce_kernel(
    const float* __restrict__ part, int S, int MN,
    const float* __restrict__ bias, const float* __restrict__ pe,
    const float* __restrict__ resid,
    const float* __restrict__ lns, const float* __restrict__ lnb,
    int relu, int N, float* __restrict__ out)
{
    const int row = blockIdx.x, t = threadIdx.x;
    const size_t idx = (size_t)row * N + t;
    float v = bias[t];
    for (int s = 0; s < S; ++s) v += part[(size_t)s * MN + idx];
    if (pe)    v += pe[(row % VIS) * N + t];
    if (resid) v += resid[idx];
    if (lns) {
        float s1 = v, s2 = v * v;
        #pragma unroll
        for (int off = 32; off; off >>= 1) {
            s1 += __shfl_xor(s1, off, 64);
            s2 += __shfl_xor(s2, off, 64);
        }
        __shared__ float red[2][4];
        const int wave = t >> 6, lane = t & 63, nw = blockDim.x >> 6;
        if (lane == 0) { red[0][wave] = s1; red[1][wave] = s2; }
        __syncthreads();
        s1 = 0.f; s2 = 0.f;
        for (int w = 0; w < nw; ++w) { s1 += red[0][w]; s2 += red[1][w]; }
        float invn = 1.f / (float)N;
        float m    = s1 * invn;
        float var  = s2 * invn - m * m;
        float inv  = 1.f / sqrtf(var + 1e-5f);
        v = (v - m) * inv * lns[t] + lnb[t];
    }
    if (relu) v = fmaxf(v, 0.f);
    out[idx] = v;
}

// ---------------- attention: sums S qkv partials + bias; block per n ----------------
__global__ __launch_bounds__(256) void attn_kernel(
    const float* __restrict__ qkvp, int S, int MN,
    const float* __restrict__ qb, float* __restrict__ out)
{
    const int n = blockIdx.x;
    const int tid = threadIdx.x;
    const int h = tid >> 5, t = tid & 31;
    const int ch = h * HD + t;
    float q[VIS], k[VIS], v[VIS];
    #pragma unroll
    for (int j = 0; j < VIS; ++j) {
        size_t idx = (size_t)(n * VIS + j) * 768 + ch;
        float qq = qb[ch], kk = qb[256 + ch], vv = qb[512 + ch];
        for (int s = 0; s < S; ++s) {
            const float* p = qkvp + (size_t)s * MN + idx;
            qq += p[0]; kk += p[256]; vv += p[512];
        }
        q[j] = qq; k[j] = kk; v[j] = vv;
    }
    const float scale = 0.1767766952966369f;  // 1/sqrt(32)
    float sm[VIS][VIS];
    #pragma unroll
    for (int qi = 0; qi < VIS; ++qi)
        #pragma unroll
        for (int ki = 0; ki < VIS; ++ki) {
            float p = q[qi] * k[ki];
            #pragma unroll
            for (int off = 16; off; off >>= 1) p += __shfl_xor(p, off, 32);
            sm[qi][ki] = p * scale;
        }
    #pragma unroll
    for (int qi = 0; qi < VIS; ++qi) {
        float mx = sm[qi][0];
        #pragma unroll
        for (int ki = 1; ki < VIS; ++ki) mx = fmaxf(mx, sm[qi][ki]);
        float e[VIS], sum = 0.f;
        #pragma unroll
        for (int ki = 0; ki < VIS; ++ki) { e[ki] = expf(sm[qi][ki] - mx); sum += e[ki]; }
        float inv = 1.f / sum;
        float acc = 0.f;
        #pragma unroll
        for (int ki = 0; ki < VIS; ++ki) acc += e[ki] * inv * v[ki];
        out[(size_t)(n * VIS + qi) * DT + ch] = acc;
    }
}

// ---------------- visit compression + ph MLP ----------------
__global__ __launch_bounds__(128) void vc_ph_kernel(
    const float* __restrict__ enc, const float* __restrict__ Wcv, const float* __restrict__ bcv,
    const float* __restrict__ mlp_w, const float* __restrict__ mlp_b,
    const float* __restrict__ mlp2_w, const float* __restrict__ mlp2_b,
    float* __restrict__ civ_out, float* __restrict__ ph_out)
{
    const int n = blockIdx.x, t = threadIdx.x;
    const int wave = t >> 6, lane = t & 63;
    float e[VIS];
    #pragma unroll
    for (int v = 0; v < VIS; ++v) e[v] = enc[(size_t)(n * VIS + v) * REP + t];
    float w = Wcv[t];
    __shared__ float part[VIS][2];
    #pragma unroll
    for (int v = 0; v < VIS; ++v) {
        float pv = e[v] * w;
        #pragma unroll
        for (int off = 32; off; off >>= 1) pv += __shfl_xor(pv, off, 64);
        if (lane == 0) part[v][wave] = pv;
    }
    __syncthreads();
    float b0 = bcv[0];
    float sc[VIS], mx = -3e38f;
    #pragma unroll
    for (int v = 0; v < VIS; ++v) { sc[v] = part[v][0] + part[v][1] + b0; mx = fmaxf(mx, sc[v]); }
    float sum = 0.f;
    #pragma unroll
    for (int v = 0; v < VIS; ++v) { sc[v] = expf(sc[v] - mx); sum += sc[v]; }
    float inv = 1.f / sum;
    float civ = 0.f;
    #pragma unroll
    for (int v = 0; v < VIS; ++v) civ += sc[v] * inv * e[v];
    civ_out[(size_t)n * REP + t] = civ;

    __shared__ float civ_s[REP];
    __shared__ float h1_s[64];
    civ_s[t] = civ;
    __syncthreads();
    if (t < 64) {
        float acc = mlp_b[t];
        #pragma unroll 8
        for (int c = 0; c < REP; ++c) acc += civ_s[c] * mlp_w[c * 64 + t];
        h1_s[t] = fmaxf(acc, 0.f);
    }
    __syncthreads();
    if (t < 64) {
        float acc = mlp2_b[t];
        #pragma unroll 8
        for (int j = 0; j < 64; ++j) acc += h1_s[j] * mlp2_w[j * 64 + t];
        ph_out[(size_t)n * 64 + t] = acc;
    }
}

// ---------------- per-event FC heads ----------------
__global__ __launch_bounds__(256) void heads_kernel(
    const float* __restrict__ civ,
    const float* __restrict__ fc1w, const float* __restrict__ fc1b,
    const float* __restrict__ fc2w, const float* __restrict__ fc2b,
    const float* __restrict__ fc3w, const float* __restrict__ fc3b,
    float* __restrict__ out)
{
    const int n = blockIdx.x >> 1, e = blockIdx.x & 1;
    const int t = threadIdx.x;
    __shared__ float civ_s[REP], h1[256], h2[128];
    if (t < REP) civ_s[t] = civ[(size_t)n * REP + t];
    __syncthreads();
    {
        float acc = fc1b[e * 256 + t];
        const float* w = fc1w + (size_t)e * REP * 256;
        #pragma unroll 8
        for (int c = 0; c < REP; ++c) acc += civ_s[c] * w[c * 256 + t];
        h1[t] = fmaxf(acc, 0.f);
    }
    __syncthreads();
    if (t < 128) {
        float acc = fc2b[e * 128 + t];
        const float* w = fc2w + (size_t)e * 256 * 128;
        #pragma unroll 8
        for (int c = 0; c < 256; ++c) acc += h1[c] * w[c * 128 + t];
        h2[t] = fmaxf(acc, 0.f);
    }
    __syncthreads();
    if (t < 64) {
        float acc = fc3b[e * 64 + t];
        const float* w = fc3w + (size_t)e * 128 * 64;
        #pragma unroll 8
        for (int c = 0; c < 128; ++c) acc += h2[c] * w[c * 64 + t];
        out[(size_t)(n * 2 + e) * 64 + t] = 1.f / (1.f + expf(-acc));
    }
}

// ---------------- launch ----------------
extern "C" void kernel_launch(void* const* d_in, const int* in_sizes, int n_in,
                              void* d_out, int out_size, void* d_ws, size_t ws_size,
                              hipStream_t stream) {
    const int*   xd1    = (const int*)  d_in[0];
    const int*   xd2    = (const int*)  d_in[1];
    const int*   xd3    = (const int*)  d_in[2];
    const int*   xr1    = (const int*)  d_in[3];
    const int*   xr2    = (const int*)  d_in[4];
    const int*   xr3    = (const int*)  d_in[5];
    const int*   xr4    = (const int*)  d_in[6];
    const float* x_demo = (const float*)d_in[7];
    const float* W_demo = (const float*)d_in[8];
    const float* b_demo = (const float*)d_in[9];
    const float* Ed1    = (const float*)d_in[10];
    const float* Ed2    = (const float*)d_in[11];
    const float* Ed3    = (const float*)d_in[12];
    const float* Er1    = (const float*)d_in[13];
    const float* Er2    = (const float*)d_in[14];
    const float* Er3    = (const float*)d_in[15];
    const float* Er4    = (const float*)d_in[16];
    const float* We_dx  = (const float*)d_in[17];
    const float* be_dx  = (const float*)d_in[18];
    const float* We_rx  = (const float*)d_in[19];
    const float* be_rx  = (const float*)d_in[20];
    const float* Wev_dx = (const float*)d_in[21];
    const float* bev_dx = (const float*)d_in[22];
    const float* Wev_rx = (const float*)d_in[23];
    const float* bev_rx = (const float*)d_in[24];
    const float* Wcv    = (const float*)d_in[25];
    const float* bcv    = (const float*)d_in[26];
    const float* enc_w1 = (const float*)d_in[27];
    const float* enc_b1 = (const float*)d_in[28];
    const float* qkv_w  = (const float*)d_in[29];
    const float* qkv_b  = (const float*)d_in[30];
    const float* ow     = (const float*)d_in[31];
    const float* ob     = (const float*)d_in[32];
    const float* ln1s   = (const float*)d_in[33];
    const float* ln1b   = (const float*)d_in[34];
    const float* ff1w   = (const float*)d_in[35];
    const float* ff1b   = (const float*)d_in[36];
    const float* ff2w   = (const float*)d_in[37];
    const float* ff2b   = (const float*)d_in[38];
    const float* ln2s   = (const float*)d_in[39];
    const float* ln2b   = (const float*)d_in[40];
    const float* enc_w2 = (const float*)d_in[41];
    const float* enc_b2 = (const float*)d_in[42];
    const float* mlp_w  = (const float*)d_in[43];
    const float* mlp_b  = (const float*)d_in[44];
    const float* mlp2_w = (const float*)d_in[45];
    const float* mlp2_b = (const float*)d_in[46];
    const float* fc1w   = (const float*)d_in[47];
    const float* fc1b   = (const float*)d_in[48];
    const float* fc2w   = (const float*)d_in[49];
    const float* fc2b   = (const float*)d_in[50];
    const float* fc3w   = (const float*)d_in[51];
    const float* fc3b   = (const float*)d_in[52];

    // workspace layout (floats): total 5,050,880 (~20.2 MB) <= proven-safe 20.6 MB
    float* ws   = (float*)d_ws;
    float* pe   = ws;                      // 1,280
    float* ccv  = pe   + 1280;             // 163,840
    float* xbuf = ccv  + 163840;           // 327,680
    float* attn = xbuf + 327680;           // 327,680
    float* enc  = attn + 327680;           // 163,840
    float* buf1 = enc  + 163840;           // 2,621,440: qkv z=2 / proj z=8 / ff1 out
    float* buf2 = buf1 + 2621440;          // 1,310,720: ff2 z=4 / enc z=8 partials
    float* proj = buf2 + 1310720;          // 134,400: per-table row projections (stride 4)
    float* A0   = buf2;                    // alias: A0 [1280,192] dead before buf2 first used

    float* pd1 = proj;                     // 1000*4
    float* pd2 = pd1 + 4000;               // 5000*4
    float* pd3 = pd2 + 20000;              // 20000*4
    float* pr1 = pd3 + 80000;              // 100*4
    float* pr2 = pr1 + 400;                // 500*4
    float* pr3 = pr2 + 2000;               // 2000*4
    float* pr4 = pr3 + 8000;               // 5000*4

    pe_kernel<<<VIS, DT, 0, stream>>>(pe);
    // per-table projections (hi = We[C:2C], lo = We[0:C], wev)
    proj_kernel<<<(1000 + 3) / 4, 256, 0, stream>>>(Ed1, We_dx, We_dx + CD, Wev_dx, 1000, pd1);
    proj_kernel<<<(5000 + 3) / 4, 256, 0, stream>>>(Ed2, We_dx, We_dx + CD, Wev_dx, 5000, pd2);
    proj_kernel<<<(20000 + 3) / 4, 256, 0, stream>>>(Ed3, We_dx, We_dx + CD, Wev_dx, 20000, pd3);
    proj_kernel<<<(100 + 3) / 4, 256, 0, stream>>>(Er1, We_rx, We_rx + CD, Wev_rx, 100, pr1);
    proj_kernel<<<(500 + 3) / 4, 256, 0, stream>>>(Er2, We_rx, We_rx + CD, Wev_rx, 500, pr2);
    proj_kernel<<<(2000 + 3) / 4, 256, 0, stream>>>(Er3, We_rx, We_rx + CD, Wev_rx, 2000, pr3);
    proj_kernel<<<(5000 + 3) / 4, 256, 0, stream>>>(Er4, We_rx, We_rx + CD, Wev_rx, 5000, pr4);

    gram_kernel<<<NV, 256, 0, stream>>>(xd1, xd2, xd3, xr1, xr2, xr3, xr4,
                                        Ed1, Ed2, Ed3, Er1, Er2, Er3, Er4,
                                        pd1, pd2, pd3, pr1, pr2, pr3, pr4,
                                        be_dx, be_rx, bev_dx, bev_rx, ccv);
    build_x0<<<NV, 192, 0, stream>>>(x_demo, W_demo, b_demo, ccv, A0);

    // x = A0 @ enc_w1 + b + pe    [1280,256], K=192, z=1
    gemm_k<<<dim3(4, 20, 1), 256, 0, stream>>>(A0, enc_w1, enc_b1, pe, xbuf,
                                               NV, DT, 192, GF_BIAS | GF_PE, 192);

    for (int i = 0; i < 4; ++i) {
        // qkv: [1280,768], K=256, z=2 (kchunk 128) -> 480 blocks; bias folded into attn
        gemm_k<<<dim3(12, 20, 2), 256, 0, stream>>>(
            xbuf, qkv_w + (size_t)i * DT * 768, nullptr, nullptr, buf1,
            NV, 768, DT, 0, 128);
        attn_kernel<<<N_PAT, 256, 0, stream>>>(buf1, 2, NV * 768, qkv_b + i * 768, attn);
        // proj: [1280,256], K=256, z=8 (kchunk 32) -> 640 blocks (into buf1, qkv dead)
        gemm_k<<<dim3(4, 20, 8), 256, 0, stream>>>(
            attn, ow + (size_t)i * DT * DT, nullptr, nullptr, buf1,
            NV, DT, DT, 0, 32);
        // sum 8 partials + ob + residual(xbuf) -> LN1 -> xbuf
        reduce_kernel<<<NV, DT, 0, stream>>>(buf1, 8, NV * DT, ob + i * DT, nullptr,
                                             xbuf, ln1s + i * DT, ln1b + i * DT, 0, DT, xbuf);
        // ff1: [1280,2048], K=256, z=1 -> 640 blocks, bias+relu in epilogue
        gemm_k<<<dim3(32, 20, 1), 256, 0, stream>>>(
            xbuf, ff1w + (size_t)i * DT * DFF, ff1b + i * DFF, nullptr, buf1,
            NV, DFF, DT, GF_BIAS | GF_RELU, DT);
        // ff2: [1280,256], K=2048, z=4 (kchunk 512) -> 320 blocks
        gemm_k<<<dim3(4, 20, 4), 256, 0, stream>>>(
            buf1, ff2w + (size_t)i * DFF * DT, nullptr, nullptr, buf2,
            NV, DT, DFF, 0, 512);
        // sum 4 partials + ff2b + residual(xbuf) -> LN2 -> xbuf
        reduce_kernel<<<NV, DT, 0, stream>>>(buf2, 4, NV * DT, ff2b + i * DT, nullptr,
                                             xbuf, ln2s + i * DT, ln2b + i * DT, 0, DT, xbuf);
    }

    // enc: [1280,128], K=256, z=8 (kchunk 32) -> 320 blocks
    gemm_k<<<dim3(2, 20, 8), 256, 0, stream>>>(xbuf, enc_w2, nullptr, nullptr, buf2,
                                               NV, REP, DT, 0, 32);
    reduce_kernel<<<NV, REP, 0, stream>>>(buf2, 8, NV * REP, enc_b2, nullptr,
                                          nullptr, nullptr, nullptr, 0, REP, enc);

    float* civ_out = (float*)d_out + 32768;          // after out [256,2,64]
    float* ph_out  = (float*)d_out + 65536;          // after civ [256,128]
    vc_ph_kernel<<<N_PAT, 128, 0, stream>>>(enc, Wcv, bcv, mlp_w, mlp_b, mlp2_w, mlp2_b,
                                            civ_out, ph_out);
    heads_kernel<<<N_PAT * 2, 256, 0, stream>>>(civ_out, fc1w, fc1b, fc2w, fc2b, fc3w, fc3b,
                                                (float*)d_out);
}

// Round 10
// 477.795 us; speedup vs baseline: 2.2534x; 1.3779x over previous
//
#include <hip/hip_runtime.h>
#include <hip/hip_bf16.h>
#include <math.h>

#define N_PAT 256
#define VIS   5
#define NV    (N_PAT*VIS)   // 1280 rows
#define DD    48            // codes per visit per modality
#define CD    128           // code dim C
#define DT    256
#define NHD   8
#define HD    32
#define DFF   2048
#define REP   128

#define GF_BIAS 1
#define GF_RELU 2
#define GF_PE   4

typedef __attribute__((ext_vector_type(8))) short short8v;
typedef __attribute__((ext_vector_type(4))) float f32x4;

__device__ __forceinline__ unsigned short f2b(float f) {
    unsigned u = __float_as_uint(f);
    return (unsigned short)((u + 0x7fffu + ((u >> 16) & 1u)) >> 16);   // RNE f32->bf16
}

// ---------------- positional encoding (5 x 256) ----------------
__global__ void pe_kernel(float* __restrict__ pe) {
    int pos = blockIdx.x, c = threadIdx.x;
    int j = c >> 1;
    float ang = (float)pos / powf(10000.f, (2.f * (float)j) / 256.f);
    pe[pos * DT + c] = (c & 1) ? cosf(ang) : sinf(ang);
}

// ---------------- weight transpose + bf16 convert: f32 [K][N] -> bf16 [N][K] ----------------
__global__ __launch_bounds__(256) void wconv_kernel(
    const float* __restrict__ in, unsigned short* __restrict__ out, int K, int N)
{
    __shared__ float t[32][33];
    const float* src = in + (size_t)blockIdx.z * K * N;
    unsigned short* dst = out + (size_t)blockIdx.z * N * K;
    int k0 = blockIdx.y * 32, n0 = blockIdx.x * 32;
    int tx = threadIdx.x & 31, ty = threadIdx.x >> 5;
    #pragma unroll
    for (int r = ty; r < 32; r += 8) t[r][tx] = src[(size_t)(k0 + r) * N + n0 + tx];
    __syncthreads();
    #pragma unroll
    for (int r = ty; r < 32; r += 8) dst[(size_t)(n0 + r) * K + k0 + tx] = f2b(t[tx][r]);
}

// ---------------- per-table row projections: hi/lo/wev dots ----------------
__global__ __launch_bounds__(256) void proj_kernel(
    const float* __restrict__ E, const float* __restrict__ W_lo,
    const float* __restrict__ W_hi, const float* __restrict__ Wev,
    int nrows, float* __restrict__ out)
{
    const int row = blockIdx.x * 4 + (threadIdx.x >> 6);
    const int lane = threadIdx.x & 63;
    if (row >= nrows) return;
    float2 e   = *(const float2*)(E + (size_t)row * CD + lane * 2);
    float2 whi = *(const float2*)(W_hi + lane * 2);
    float2 wlo = *(const float2*)(W_lo + lane * 2);
    float2 wev = *(const float2*)(Wev + lane * 2);
    float ph = e.x * whi.x + e.y * whi.y;
    float pl = e.x * wlo.x + e.y * wlo.y;
    float pw = e.x * wev.x + e.y * wev.y;
    #pragma unroll
    for (int off = 32; off; off >>= 1) {
        ph += __shfl_xor(ph, off, 64);
        pl += __shfl_xor(pl, off, 64);
        pw += __shfl_xor(pw, off, 64);
    }
    if (lane == 0) {
        out[(size_t)row * 4 + 0] = ph;
        out[(size_t)row * 4 + 1] = pl;
        out[(size_t)row * 4 + 2] = pw;
        out[(size_t)row * 4 + 3] = 0.f;
    }
}

// ---------------- GRAM via precomputed projections ----------------
__global__ __launch_bounds__(256) void gram_kernel(
    const int* __restrict__ xd1, const int* __restrict__ xd2, const int* __restrict__ xd3,
    const int* __restrict__ xr1, const int* __restrict__ xr2, const int* __restrict__ xr3,
    const int* __restrict__ xr4,
    const float* __restrict__ Ed1, const float* __restrict__ Ed2, const float* __restrict__ Ed3,
    const float* __restrict__ Er1, const float* __restrict__ Er2, const float* __restrict__ Er3,
    const float* __restrict__ Er4,
    const float* __restrict__ pd1, const float* __restrict__ pd2, const float* __restrict__ pd3,
    const float* __restrict__ pr1, const float* __restrict__ pr2, const float* __restrict__ pr3,
    const float* __restrict__ pr4,
    const float* __restrict__ be_dx, const float* __restrict__ be_rx,
    const float* __restrict__ bev_dx, const float* __restrict__ bev_rx,
    float* __restrict__ ccv)
{
    __shared__ float aw[96][4];
    __shared__ float ev[96];
    __shared__ int   sidx[96][4];
    __shared__ float part[4][128];
    const int nv   = blockIdx.x;
    const int tid  = threadIdx.x;
    const int wave = tid >> 6, lane = tid & 63;
    const int base = nv * DD;

    if (tid < 48) {
        const int d = tid;
        const int i1 = xd1[base + d], i2 = xd2[base + d], i3 = xd3[base + d];
        sidx[d][0] = i1; sidx[d][1] = i2; sidx[d][2] = i3;
        float4 q1 = *(const float4*)(pd1 + (size_t)i1 * 4);
        float4 q2 = *(const float4*)(pd2 + (size_t)i2 * 4);
        float4 q3 = *(const float4*)(pd3 + (size_t)i3 * 4);
        const float be = be_dx[0];
        const float p0 = q3.y;
        float s1 = fmaxf(p0 + q1.x + be, 0.f);
        float s2 = fmaxf(p0 + q2.x + be, 0.f);
        float s3 = fmaxf(p0 + q3.x + be, 0.f);
        float a1, a2, a3;
        if (i1 != 0) {
            float mx = fmaxf(s1, fmaxf(s2, s3));
            a1 = expf(s1 - mx); a2 = expf(s2 - mx); a3 = expf(s3 - mx);
        } else {
            a1 = a2 = a3 = 1.f;
        }
        float inv = 1.f / (a1 + a2 + a3);
        a1 *= inv; a2 *= inv; a3 *= inv;
        aw[d][0] = a1; aw[d][1] = a2; aw[d][2] = a3; aw[d][3] = 0.f;
        ev[d] = (i1 != 0) ? (a1 * q1.z + a2 * q2.z + a3 * q3.z + bev_dx[0]) : -1e20f;
    } else if (tid >= 64 && tid < 112) {
        const int d = tid - 64;
        const int i1 = xr1[base + d], i2 = xr2[base + d], i3 = xr3[base + d], i4 = xr4[base + d];
        const int m = 48 + d;
        sidx[m][0] = i1; sidx[m][1] = i2; sidx[m][2] = i3; sidx[m][3] = i4;
        float4 q1 = *(const float4*)(pr1 + (size_t)i1 * 4);
        float4 q2 = *(const float4*)(pr2 + (size_t)i2 * 4);
        float4 q3 = *(const float4*)(pr3 + (size_t)i3 * 4);
        float4 q4 = *(const float4*)(pr4 + (size_t)i4 * 4);
        const float be = be_rx[0];
        const float p0 = q4.y;
        float s1 = fmaxf(p0 + q1.x + be, 0.f);
        float s2 = fmaxf(p0 + q2.x + be, 0.f);
        float s3 = fmaxf(p0 + q3.x + be, 0.f);
        float s4 = fmaxf(p0 + q4.x + be, 0.f);
        float a1, a2, a3, a4;
        if (i1 != 0) {
            float mx = fmaxf(fmaxf(s1, s2), fmaxf(s3, s4));
            a1 = expf(s1 - mx); a2 = expf(s2 - mx); a3 = expf(s3 - mx); a4 = expf(s4 - mx);
        } else {
            a1 = a2 = a3 = a4 = 1.f;
        }
        float inv = 1.f / (a1 + a2 + a3 + a4);
        aw[m][0] = a1 * inv; aw[m][1] = a2 * inv; aw[m][2] = a3 * inv; aw[m][3] = a4 * inv;
        ev[m] = (i1 != 0) ? ((a1 * q1.z + a2 * q2.z + a3 * q3.z + a4 * q4.z) * inv + bev_rx[0])
                          : -1e20f;
    }
    __syncthreads();

    if (wave == 0) {
        float a = ev[lane];
        float b = (lane < 32) ? ev[64 + lane] : -3.0e38f;
        float mx = fmaxf(a, b);
        #pragma unroll
        for (int off = 32; off; off >>= 1) mx = fmaxf(mx, __shfl_xor(mx, off, 64));
        float ea = expf(a - mx);
        float eb = (lane < 32) ? expf(b - mx) : 0.f;
        float s = ea + eb;
        #pragma unroll
        for (int off = 32; off; off >>= 1) s += __shfl_xor(s, off, 64);
        float inv = 1.f / s;
        ev[lane] = ea * inv;
        if (lane < 32) ev[64 + lane] = eb * inv;
    }
    __syncthreads();

    if (tid < 96) {
        float av = ev[tid];
        aw[tid][0] *= av; aw[tid][1] *= av; aw[tid][2] *= av; aw[tid][3] *= av;
    }
    __syncthreads();

    float accx = 0.f, accy = 0.f;
    const int co = lane * 2;
    for (int m = wave; m < 96; m += 4) {
        if (m < 48) {
            int i1 = sidx[m][0], i2 = sidx[m][1], i3 = sidx[m][2];
            float2 e1 = *(const float2*)(Ed1 + (size_t)i1 * CD + co);
            float2 e2 = *(const float2*)(Ed2 + (size_t)i2 * CD + co);
            float2 e3 = *(const float2*)(Ed3 + (size_t)i3 * CD + co);
            float w1 = aw[m][0], w2 = aw[m][1], w3 = aw[m][2];
            accx += w1 * e1.x + w2 * e2.x + w3 * e3.x;
            accy += w1 * e1.y + w2 * e2.y + w3 * e3.y;
        } else {
            int i1 = sidx[m][0], i2 = sidx[m][1], i3 = sidx[m][2], i4 = sidx[m][3];
            float2 e1 = *(const float2*)(Er1 + (size_t)i1 * CD + co);
            float2 e2 = *(const float2*)(Er2 + (size_t)i2 * CD + co);
            float2 e3 = *(const float2*)(Er3 + (size_t)i3 * CD + co);
            float2 e4 = *(const float2*)(Er4 + (size_t)i4 * CD + co);
            float w1 = aw[m][0], w2 = aw[m][1], w3 = aw[m][2], w4 = aw[m][3];
            accx += w1 * e1.x + w2 * e2.x + w3 * e3.x + w4 * e4.x;
            accy += w1 * e1.y + w2 * e2.y + w3 * e3.y + w4 * e4.y;
        }
    }
    part[wave][co]     = accx;
    part[wave][co + 1] = accy;
    __syncthreads();
    if (tid < CD) {
        ccv[(size_t)nv * CD + tid] =
            part[0][tid] + part[1][tid] + part[2][tid] + part[3][tid];
    }
}

// ---------------- build x0 (bf16) = [relu(x_demo@W_demo+b), ccv] : [1280,192] ----------------
__global__ __launch_bounds__(192) void build_x0(
    const float* __restrict__ x_demo, const float* __restrict__ W_demo,
    const float* __restrict__ b_demo, const float* __restrict__ ccv,
    unsigned short* __restrict__ A0bf)
{
    int row = blockIdx.x, j = threadIdx.x;
    float v;
    if (j < 64) {
        float acc = b_demo[j];
        #pragma unroll
        for (int f = 0; f < 32; ++f) acc += x_demo[row * 32 + f] * W_demo[f * 64 + j];
        v = fmaxf(acc, 0.f);
    } else {
        v = ccv[row * CD + (j - 64)];
    }
    A0bf[row * 192 + j] = f2b(v);
}

// ---------------- bf16 MFMA GEMM (64x64 tile, BK=32, 4 waves, split-K capable) ----------------
// A [M][K] bf16 row-major, B [N][K] bf16 (transposed weights).
// z==1: epilogue bias/pe/relu, writes f32 Cf and/or bf16 Cb.
// z>1 : raw f32 partials to Cf + z*M*N.
__global__ __launch_bounds__(256) void gemm_bf(
    const unsigned short* __restrict__ A, const unsigned short* __restrict__ B,
    const float* __restrict__ bias, const float* __restrict__ pe,
    float* __restrict__ Cf, unsigned short* __restrict__ Cb,
    int M, int N, int K, int flags, int kchunk)
{
    __shared__ unsigned short As[64][40];   // pad 40: fragment reads 2-way aliased (free)
    __shared__ unsigned short Bs[64][40];
    const int bm = blockIdx.y * 64, bn = blockIdx.x * 64;
    const int tid = threadIdx.x;
    const int wave = tid >> 6, lane = tid & 63;
    const int wr = (wave >> 1) * 32, wc = (wave & 1) * 32;
    const int l15 = lane & 15, l4 = lane >> 4;
    const int srow = tid >> 2, sk8 = (tid & 3) * 8;
    const int kbeg = blockIdx.z * kchunk, kend = kbeg + kchunk;
    f32x4 acc[2][2] = {};

    for (int k0 = kbeg; k0 < kend; k0 += 32) {
        *(short8v*)&As[srow][sk8] = *(const short8v*)(A + (size_t)(bm + srow) * K + k0 + sk8);
        *(short8v*)&Bs[srow][sk8] = *(const short8v*)(B + (size_t)(bn + srow) * K + k0 + sk8);
        __syncthreads();
        short8v a0 = *(const short8v*)&As[wr + l15][l4 * 8];
        short8v a1 = *(const short8v*)&As[wr + 16 + l15][l4 * 8];
        short8v b0 = *(const short8v*)&Bs[wc + l15][l4 * 8];
        short8v b1 = *(const short8v*)&Bs[wc + 16 + l15][l4 * 8];
        acc[0][0] = __builtin_amdgcn_mfma_f32_16x16x32_bf16(a0, b0, acc[0][0], 0, 0, 0);
        acc[0][1] = __builtin_amdgcn_mfma_f32_16x16x32_bf16(a0, b1, acc[0][1], 0, 0, 0);
        acc[1][0] = __builtin_amdgcn_mfma_f32_16x16x32_bf16(a1, b0, acc[1][0], 0, 0, 0);
        acc[1][1] = __builtin_amdgcn_mfma_f32_16x16x32_bf16(a1, b1, acc[1][1], 0, 0, 0);
        __syncthreads();
    }

    if (gridDim.z == 1) {
        #pragma unroll
        for (int mi = 0; mi < 2; ++mi)
            #pragma unroll
            for (int ni = 0; ni < 2; ++ni) {
                int col = bn + wc + ni * 16 + l15;
                float bz = (flags & GF_BIAS) ? bias[col] : 0.f;
                #pragma unroll
                for (int r = 0; r < 4; ++r) {
                    int row = bm + wr + mi * 16 + l4 * 4 + r;
                    float v = acc[mi][ni][r] + bz;
                    if (flags & GF_PE)   v += pe[(row % VIS) * N + col];
                    if (flags & GF_RELU) v = fmaxf(v, 0.f);
                    if (Cf) Cf[(size_t)row * N + col] = v;
                    if (Cb) Cb[(size_t)row * N + col] = f2b(v);
                }
            }
    } else {
        float* Cp = Cf + (size_t)blockIdx.z * M * N;
        #pragma unroll
        for (int mi = 0; mi < 2; ++mi)
            #pragma unroll
            for (int ni = 0; ni < 2; ++ni) {
                int col = bn + wc + ni * 16 + l15;
                #pragma unroll
                for (int r = 0; r < 4; ++r) {
                    int row = bm + wr + mi * 16 + l4 * 4 + r;
                    Cp[(size_t)row * N + col] = acc[mi][ni][r];
                }
            }
    }
}

// ---------------- f32 tiled GEMM (kept for enc_w2; split-K) ----------------
__global__ __launch_bounds__(256) void gemm_k(
    const float* __restrict__ A, const float* __restrict__ B,
    const float* __restrict__ bias, const float* __restrict__ pe,
    float* __restrict__ C, int M, int N, int K, int flags, int kchunk)
{
    __shared__ float As[16][68];
    __shared__ float Bs[16][64];
    const int bm = blockIdx.y * 64, bn = blockIdx.x * 64;
    const int tid = threadIdx.x;
    const int tx = tid & 15, ty = tid >> 4;
    const int kbeg = blockIdx.z * kchunk;
    const int kend = kbeg + kchunk;
    const int ar  = tid >> 2, akc = (tid & 3) * 4;
    const int bbr = tid >> 4, bbc = (tid & 15) * 4;
    float acc[4][4] = {{0.f}};

    for (int k0 = kbeg; k0 < kend; k0 += 16) {
        float4 va = *(const float4*)(A + (size_t)(bm + ar) * K + k0 + akc);
        float4 vb = *(const float4*)(B + (size_t)(k0 + bbr) * N + bn + bbc);
        As[akc + 0][ar] = va.x;
        As[akc + 1][ar] = va.y;
        As[akc + 2][ar] = va.z;
        As[akc + 3][ar] = va.w;
        *(float4*)&Bs[bbr][bbc] = vb;
        __syncthreads();
        #pragma unroll
        for (int kk = 0; kk < 16; ++kk) {
            float4 a = *(const float4*)&As[kk][ty * 4];
            float4 b = *(const float4*)&Bs[kk][tx * 4];
            acc[0][0] += a.x * b.x; acc[0][1] += a.x * b.y; acc[0][2] += a.x * b.z; acc[0][3] += a.x * b.w;
            acc[1][0] += a.y * b.x; acc[1][1] += a.y * b.y; acc[1][2] += a.y * b.z; acc[1][3] += a.y * b.w;
            acc[2][0] += a.z * b.x; acc[2][1] += a.z * b.y; acc[2][2] += a.z * b.z; acc[2][3] += a.z * b.w;
            acc[3][0] += a.w * b.x; acc[3][1] += a.w * b.y; acc[3][2] += a.w * b.z; acc[3][3] += a.w * b.w;
        }
        __syncthreads();
    }

    if (gridDim.z == 1) {
        #pragma unroll
        for (int i = 0; i < 4; ++i) {
            int row = bm + ty * 4 + i;
            int col0 = bn + tx * 4;
            float4 v = *(float4*)&acc[i][0];
            if (flags & GF_BIAS) {
                const float4 bz = *(const float4*)(bias + col0);
                v.x += bz.x; v.y += bz.y; v.z += bz.z; v.w += bz.w;
            }
            if (flags & GF_PE) {
                const float4 pz = *(const float4*)(pe + (row % VIS) * N + col0);
                v.x += pz.x; v.y += pz.y; v.z += pz.z; v.w += pz.w;
            }
            if (flags & GF_RELU) {
                v.x = fmaxf(v.x, 0.f); v.y = fmaxf(v.y, 0.f);
                v.z = fmaxf(v.z, 0.f); v.w = fmaxf(v.w, 0.f);
            }
            *(float4*)(C + (size_t)row * N + col0) = v;
        }
    } else {
        float* Cp = C + (size_t)blockIdx.z * M * N;
        #pragma unroll
        for (int i = 0; i < 4; ++i) {
            int row = bm + ty * 4 + i;
            *(float4*)(Cp + (size_t)row * N + bn + tx * 4) = *(float4*)&acc[i][0];
        }
    }
}

// ---------------- split-K reduce + bias (+resid) (+LN) ; optional bf16 mirror ----------------
__global__ void reduce_kernel(
    const float* __restrict__ part, int S, int MN,
    const float* __restrict__ bias,
    const float* __restrict__ resid,
    const float* __restrict__ lns, const float* __restrict__ lnb,
    int N, float* __restrict__ out, unsigned short* __restrict__ out_bf)
{
    const int row = blockIdx.x, t = threadIdx.x;
    const size_t idx = (size_t)row * N + t;
    float v = bias[t];
    for (int s = 0; s < S; ++s) v += part[(size_t)s * MN + idx];
    if (resid) v += resid[idx];
    if (lns) {
        float s1 = v, s2 = v * v;
        #pragma unroll
        for (int off = 32; off; off >>= 1) {
            s1 += __shfl_xor(s1, off, 64);
            s2 += __shfl_xor(s2, off, 64);
        }
        __shared__ float red[2][4];
        const int wave = t >> 6, lane = t & 63, nw = blockDim.x >> 6;
        if (lane == 0) { red[0][wave] = s1; red[1][wave] = s2; }
        __syncthreads();
        s1 = 0.f; s2 = 0.f;
        for (int w = 0; w < nw; ++w) { s1 += red[0][w]; s2 += red[1][w]; }
        float invn = 1.f / (float)N;
        float m    = s1 * invn;
        float var  = s2 * invn - m * m;
        float inv  = 1.f / sqrtf(var + 1e-5f);
        v = (v - m) * inv * lns[t] + lnb[t];
    }
    out[idx] = v;
    if (out_bf) out_bf[idx] = f2b(v);
}

// ---------------- attention (bias already applied by qkv GEMM); writes bf16 ----------------
__global__ __launch_bounds__(256) void attn_kernel(
    const float* __restrict__ qkv, unsigned short* __restrict__ out)
{
    const int n = blockIdx.x;
    const int tid = threadIdx.x;
    const int h = tid >> 5, t = tid & 31;
    const int ch = h * HD + t;
    float q[VIS], k[VIS], v[VIS];
    #pragma unroll
    for (int j = 0; j < VIS; ++j) {
        const float* row = qkv + (size_t)(n * VIS + j) * 768 + ch;
        q[j] = row[0]; k[j] = row[256]; v[j] = row[512];
    }
    const float scale = 0.1767766952966369f;  // 1/sqrt(32)
    float sm[VIS][VIS];
    #pragma unroll
    for (int qi = 0; qi < VIS; ++qi)
        #pragma unroll
        for (int ki = 0; ki < VIS; ++ki) {
            float p = q[qi] * k[ki];
            #pragma unroll
            for (int off = 16; off; off >>= 1) p += __shfl_xor(p, off, 32);
            sm[qi][ki] = p * scale;
        }
    #pragma unroll
    for (int qi = 0; qi < VIS; ++qi) {
        float mx = sm[qi][0];
        #pragma unroll
        for (int ki = 1; ki < VIS; ++ki) mx = fmaxf(mx, sm[qi][ki]);
        float e[VIS], sum = 0.f;
        #pragma unroll
        for (int ki = 0; ki < VIS; ++ki) { e[ki] = expf(sm[qi][ki] - mx); sum += e[ki]; }
        float inv = 1.f / sum;
        float acc = 0.f;
        #pragma unroll
        for (int ki = 0; ki < VIS; ++ki) acc += e[ki] * inv * v[ki];
        out[(size_t)(n * VIS + qi) * DT + ch] = f2b(acc);
    }
}

// ---------------- visit compression + ph MLP ----------------
__global__ __launch_bounds__(128) void vc_ph_kernel(
    const float* __restrict__ enc, const float* __restrict__ Wcv, const float* __restrict__ bcv,
    const float* __restrict__ mlp_w, const float* __restrict__ mlp_b,
    const float* __restrict__ mlp2_w, const float* __restrict__ mlp2_b,
    float* __restrict__ civ_out, float* __restrict__ ph_out)
{
    const int n = blockIdx.x, t = threadIdx.x;
    const int wave = t >> 6, lane = t & 63;
    float e[VIS];
    #pragma unroll
    for (int v = 0; v < VIS; ++v) e[v] = enc[(size_t)(n * VIS + v) * REP + t];
    float w = Wcv[t];
    __shared__ float part[VIS][2];
    #pragma unroll
    for (int v = 0; v < VIS; ++v) {
        float pv = e[v] * w;
        #pragma unroll
        for (int off = 32; off; off >>= 1) pv += __shfl_xor(pv, off, 64);
        if (lane == 0) part[v][wave] = pv;
    }
    __syncthreads();
    float b0 = bcv[0];
    float sc[VIS], mx = -3e38f;
    #pragma unroll
    for (int v = 0; v < VIS; ++v) { sc[v] = part[v][0] + part[v][1] + b0; mx = fmaxf(mx, sc[v]); }
    float sum = 0.f;
    #pragma unroll
    for (int v = 0; v < VIS; ++v) { sc[v] = expf(sc[v] - mx); sum += sc[v]; }
    float inv = 1.f / sum;
    float civ = 0.f;
    #pragma unroll
    for (int v = 0; v < VIS; ++v) civ += sc[v] * inv * e[v];
    civ_out[(size_t)n * REP + t] = civ;

    __shared__ float civ_s[REP];
    __shared__ float h1_s[64];
    civ_s[t] = civ;
    __syncthreads();
    if (t < 64) {
        float acc = mlp_b[t];
        #pragma unroll 8
        for (int c = 0; c < REP; ++c) acc += civ_s[c] * mlp_w[c * 64 + t];
        h1_s[t] = fmaxf(acc, 0.f);
    }
    __syncthreads();
    if (t < 64) {
        float acc = mlp2_b[t];
        #pragma unroll 8
        for (int j = 0; j < 64; ++j) acc += h1_s[j] * mlp2_w[j * 64 + t];
        ph_out[(size_t)n * 64 + t] = acc;
    }
}

// ---------------- per-event FC heads ----------------
__global__ __launch_bounds__(256) void heads_kernel(
    const float* __restrict__ civ,
    const float* __restrict__ fc1w, const float* __restrict__ fc1b,
    const float* __restrict__ fc2w, const float* __restrict__ fc2b,
    const float* __restrict__ fc3w, const float* __restrict__ fc3b,
    float* __restrict__ out)
{
    const int n = blockIdx.x >> 1, e = blockIdx.x & 1;
    const int t = threadIdx.x;
    __shared__ float civ_s[REP], h1[256], h2[128];
    if (t < REP) civ_s[t] = civ[(size_t)n * REP + t];
    __syncthreads();
    {
        float acc = fc1b[e * 256 + t];
        const float* w = fc1w + (size_t)e * REP * 256;
        #pragma unroll 8
        for (int c = 0; c < REP; ++c) acc += civ_s[c] * w[c * 256 + t];
        h1[t] = fmaxf(acc, 0.f);
    }
    __syncthreads();
    if (t < 128) {
        float acc = fc2b[e * 128 + t];
        const float* w = fc2w + (size_t)e * 256 * 128;
        #pragma unroll 8
        for (int c = 0; c < 256; ++c) acc += h1[c] * w[c * 128 + t];
        h2[t] = fmaxf(acc, 0.f);
    }
    __syncthreads();
    if (t < 64) {
        float acc = fc3b[e * 64 + t];
        const float* w = fc3w + (size_t)e * 128 * 64;
        #pragma unroll 8
        for (int c = 0; c < 128; ++c) acc += h2[c] * w[c * 64 + t];
        out[(size_t)(n * 2 + e) * 64 + t] = 1.f / (1.f + expf(-acc));
    }
}

// ---------------- launch ----------------
extern "C" void kernel_launch(void* const* d_in, const int* in_sizes, int n_in,
                              void* d_out, int out_size, void* d_ws, size_t ws_size,
                              hipStream_t stream) {
    const int*   xd1    = (const int*)  d_in[0];
    const int*   xd2    = (const int*)  d_in[1];
    const int*   xd3    = (const int*)  d_in[2];
    const int*   xr1    = (const int*)  d_in[3];
    const int*   xr2    = (const int*)  d_in[4];
    const int*   xr3    = (const int*)  d_in[5];
    const int*   xr4    = (const int*)  d_in[6];
    const float* x_demo = (const float*)d_in[7];
    const float* W_demo = (const float*)d_in[8];
    const float* b_demo = (const float*)d_in[9];
    const float* Ed1    = (const float*)d_in[10];
    const float* Ed2    = (const float*)d_in[11];
    const float* Ed3    = (const float*)d_in[12];
    const float* Er1    = (const float*)d_in[13];
    const float* Er2    = (const float*)d_in[14];
    const float* Er3    = (const float*)d_in[15];
    const float* Er4    = (const float*)d_in[16];
    const float* We_dx  = (const float*)d_in[17];
    const float* be_dx  = (const float*)d_in[18];
    const float* We_rx  = (const float*)d_in[19];
    const float* be_rx  = (const float*)d_in[20];
    const float* Wev_dx = (const float*)d_in[21];
    const float* bev_dx = (const float*)d_in[22];
    const float* Wev_rx = (const float*)d_in[23];
    const float* bev_rx = (const float*)d_in[24];
    const float* Wcv    = (const float*)d_in[25];
    const float* bcv    = (const float*)d_in[26];
    const float* enc_w1 = (const float*)d_in[27];
    const float* enc_b1 = (const float*)d_in[28];
    const float* qkv_w  = (const float*)d_in[29];
    const float* qkv_b  = (const float*)d_in[30];
    const float* ow     = (const float*)d_in[31];
    const float* ob     = (const float*)d_in[32];
    const float* ln1s   = (const float*)d_in[33];
    const float* ln1b   = (const float*)d_in[34];
    const float* ff1w   = (const float*)d_in[35];
    const float* ff1b   = (const float*)d_in[36];
    const float* ff2w   = (const float*)d_in[37];
    const float* ff2b   = (const float*)d_in[38];
    const float* ln2s   = (const float*)d_in[39];
    const float* ln2b   = (const float*)d_in[40];
    const float* enc_w2 = (const float*)d_in[41];
    const float* enc_b2 = (const float*)d_in[42];
    const float* mlp_w  = (const float*)d_in[43];
    const float* mlp_b  = (const float*)d_in[44];
    const float* mlp2_w = (const float*)d_in[45];
    const float* mlp2_b = (const float*)d_in[46];
    const float* fc1w   = (const float*)d_in[47];
    const float* fc1b   = (const float*)d_in[48];
    const float* fc2w   = (const float*)d_in[49];
    const float* fc2b   = (const float*)d_in[50];
    const float* fc3w   = (const float*)d_in[51];
    const float* fc3b   = (const float*)d_in[52];

    // workspace (ws_size ~256 MiB per round-6 fill profile; we use ~31 MB)
    float* ws     = (float*)d_ws;
    float* pe     = ws;                       // 1,280
    float* ccv    = pe + 1280;                // 163,840
    float* xbuf   = ccv + 163840;             // 327,680
    float* qkvbuf = xbuf + 327680;            // 983,040
    float* projbf = qkvbuf + 983040;          // 327,680 (proj f32 out)
    float* enc    = projbf + 327680;          // 163,840
    float* buf2   = enc + 163840;             // 1,310,720 (ff2 z=4 / enc_w2 z=8 partials)
    float* ptab   = buf2 + 1310720;           // 134,400 (projection tables)
    unsigned short* usb = (unsigned short*)(ptab + 134400);
    unsigned short* A0bf    = usb;                     // 245,760
    unsigned short* xbuf_bf = A0bf + 245760;           // 327,680
    unsigned short* attn_bf = xbuf_bf + 327680;        // 327,680
    unsigned short* ff1_bf  = attn_bf + 327680;        // 2,621,440
    unsigned short* qkv_wt  = ff1_bf + 2621440;        // 786,432  [768][256] x4
    unsigned short* ow_t    = qkv_wt + 786432;         // 262,144  [256][256] x4
    unsigned short* ff1_wt  = ow_t + 262144;           // 2,097,152 [2048][256] x4
    unsigned short* ff2_wt  = ff1_wt + 2097152;        // 2,097,152 [256][2048] x4
    unsigned short* ew1_t   = ff2_wt + 2097152;        // 49,152   [256][192]

    float* pd1 = ptab;
    float* pd2 = pd1 + 4000;
    float* pd3 = pd2 + 20000;
    float* pr1 = pd3 + 80000;
    float* pr2 = pr1 + 400;
    float* pr3 = pr2 + 2000;
    float* pr4 = pr3 + 8000;

    pe_kernel<<<VIS, DT, 0, stream>>>(pe);

    // weight transpose+bf16 conversions: f32 [K][N] -> bf16 [N][K]
    wconv_kernel<<<dim3(24, 8, 4), 256, 0, stream>>>(qkv_w, qkv_wt, 256, 768);
    wconv_kernel<<<dim3(8, 8, 4), 256, 0, stream>>>(ow, ow_t, 256, 256);
    wconv_kernel<<<dim3(64, 8, 4), 256, 0, stream>>>(ff1w, ff1_wt, 256, 2048);
    wconv_kernel<<<dim3(8, 64, 4), 256, 0, stream>>>(ff2w, ff2_wt, 2048, 256);
    wconv_kernel<<<dim3(8, 6, 1), 256, 0, stream>>>(enc_w1, ew1_t, 192, 256);

    proj_kernel<<<(1000 + 3) / 4, 256, 0, stream>>>(Ed1, We_dx, We_dx + CD, Wev_dx, 1000, pd1);
    proj_kernel<<<(5000 + 3) / 4, 256, 0, stream>>>(Ed2, We_dx, We_dx + CD, Wev_dx, 5000, pd2);
    proj_kernel<<<(20000 + 3) / 4, 256, 0, stream>>>(Ed3, We_dx, We_dx + CD, Wev_dx, 20000, pd3);
    proj_kernel<<<(100 + 3) / 4, 256, 0, stream>>>(Er1, We_rx, We_rx + CD, Wev_rx, 100, pr1);
    proj_kernel<<<(500 + 3) / 4, 256, 0, stream>>>(Er2, We_rx, We_rx + CD, Wev_rx, 500, pr2);
    proj_kernel<<<(2000 + 3) / 4, 256, 0, stream>>>(Er3, We_rx, We_rx + CD, Wev_rx, 2000, pr3);
    proj_kernel<<<(5000 + 3) / 4, 256, 0, stream>>>(Er4, We_rx, We_rx + CD, Wev_rx, 5000, pr4);

    gram_kernel<<<NV, 256, 0, stream>>>(xd1, xd2, xd3, xr1, xr2, xr3, xr4,
                                        Ed1, Ed2, Ed3, Er1, Er2, Er3, Er4,
                                        pd1, pd2, pd3, pr1, pr2, pr3, pr4,
                                        be_dx, be_rx, bev_dx, bev_rx, ccv);
    build_x0<<<NV, 192, 0, stream>>>(x_demo, W_demo, b_demo, ccv, A0bf);

    // x = A0 @ enc_w1 + b + pe  (MFMA): writes f32 xbuf + bf16 xbuf_bf
    gemm_bf<<<dim3(4, 20, 1), 256, 0, stream>>>(A0bf, ew1_t, enc_b1, pe,
                                                xbuf, xbuf_bf, NV, DT, 192,
                                                GF_BIAS | GF_PE, 192);

    for (int i = 0; i < 4; ++i) {
        // qkv (MFMA, bias fused): [1280,768] K=256 -> 240 blocks
        gemm_bf<<<dim3(12, 20, 1), 256, 0, stream>>>(
            xbuf_bf, qkv_wt + (size_t)i * 768 * 256, qkv_b + i * 768, nullptr,
            qkvbuf, nullptr, NV, 768, DT, GF_BIAS, DT);
        attn_kernel<<<N_PAT, 256, 0, stream>>>(qkvbuf, attn_bf);
        // proj (MFMA raw): [1280,256] K=256 -> 80 blocks
        gemm_bf<<<dim3(4, 20, 1), 256, 0, stream>>>(
            attn_bf, ow_t + (size_t)i * 256 * 256, nullptr, nullptr,
            projbf, nullptr, NV, DT, DT, 0, DT);
        // + ob + residual -> LN1 -> xbuf / xbuf_bf
        reduce_kernel<<<NV, DT, 0, stream>>>(projbf, 1, NV * DT, ob + i * DT,
                                             xbuf, ln1s + i * DT, ln1b + i * DT,
                                             DT, xbuf, xbuf_bf);
        // ff1 (MFMA, bias+relu): [1280,2048] K=256 -> 640 blocks, bf16 out only
        gemm_bf<<<dim3(32, 20, 1), 256, 0, stream>>>(
            xbuf_bf, ff1_wt + (size_t)i * DFF * 256, ff1b + i * DFF, nullptr,
            nullptr, ff1_bf, NV, DFF, DT, GF_BIAS | GF_RELU, DT);
        // ff2 (MFMA split-K z=4): [1280,256] K=2048 -> 320 blocks
        gemm_bf<<<dim3(4, 20, 4), 256, 0, stream>>>(
            ff1_bf, ff2_wt + (size_t)i * 256 * DFF, nullptr, nullptr,
            buf2, nullptr, NV, DT, DFF, 0, 512);
        // + ff2b + residual -> LN2 -> xbuf / xbuf_bf
        reduce_kernel<<<NV, DT, 0, stream>>>(buf2, 4, NV * DT, ff2b + i * DT,
                                             xbuf, ln2s + i * DT, ln2b + i * DT,
                                             DT, xbuf, xbuf_bf);
    }

    // enc: f32 path (output-adjacent): [1280,128] K=256, z=8
    gemm_k<<<dim3(2, 20, 8), 256, 0, stream>>>(xbuf, enc_w2, nullptr, nullptr, buf2,
                                               NV, REP, DT, 0, 32);
    reduce_kernel<<<NV, REP, 0, stream>>>(buf2, 8, NV * REP, enc_b2,
                                          nullptr, nullptr, nullptr, REP, enc, nullptr);

    float* civ_out = (float*)d_out + 32768;
    float* ph_out  = (float*)d_out + 65536;
    vc_ph_kernel<<<N_PAT, 128, 0, stream>>>(enc, Wcv, bcv, mlp_w, mlp_b, mlp2_w, mlp2_b,
                                            civ_out, ph_out);
    heads_kernel<<<N_PAT * 2, 256, 0, stream>>>(civ_out, fc1w, fc1b, fc2w, fc2b, fc3w, fc3b,
                                                (float*)d_out);
}

// Round 12
// 477.337 us; speedup vs baseline: 2.2555x; 1.0010x over previous
//
#include <hip/hip_runtime.h>
#include <hip/hip_bf16.h>
#include <math.h>

#define N_PAT 256
#define VIS   5
#define NV    (N_PAT*VIS)   // 1280 rows
#define DD    48
#define CD    128
#define DT    256
#define HD    32
#define DFF   2048
#define REP   128

#define GF_BIAS 1
#define GF_RELU 2
#define GF_PE   4

typedef __attribute__((ext_vector_type(8))) short short8v;
typedef __attribute__((ext_vector_type(4))) float f32x4;

__device__ __forceinline__ unsigned short f2b(float f) {
    unsigned u = __float_as_uint(f);
    return (unsigned short)((u + 0x7fffu + ((u >> 16) & 1u)) >> 16);   // RNE f32->bf16
}

// ---------------- prep: pe (blocks 0-4) + all 7 projection tables (wave per row) ----------------
__global__ __launch_bounds__(256) void prep_kernel(
    const float* __restrict__ Ed1, const float* __restrict__ Ed2, const float* __restrict__ Ed3,
    const float* __restrict__ Er1, const float* __restrict__ Er2, const float* __restrict__ Er3,
    const float* __restrict__ Er4,
    const float* __restrict__ We_dx, const float* __restrict__ We_rx,
    const float* __restrict__ Wev_dx, const float* __restrict__ Wev_rx,
    float* __restrict__ pe,
    float* __restrict__ pd1, float* __restrict__ pd2, float* __restrict__ pd3,
    float* __restrict__ pr1, float* __restrict__ pr2, float* __restrict__ pr3,
    float* __restrict__ pr4)
{
    const int b = blockIdx.x;
    if (b < VIS) {                       // positional encoding rows
        int c = threadIdx.x, j = c >> 1;
        float ang = (float)b / powf(10000.f, (2.f * (float)j) / 256.f);
        pe[b * DT + c] = (c & 1) ? cosf(ang) : sinf(ang);
        return;
    }
    const int g = (b - VIS) * 4 + (threadIdx.x >> 6);   // global row over all tables
    const int lane = threadIdx.x & 63;
    if (g >= 33600) return;
    const float* E; float* out; int loc; int isdx;
    if      (g < 1000)  { E = Ed1; out = pd1; loc = g;          isdx = 1; }
    else if (g < 6000)  { E = Ed2; out = pd2; loc = g - 1000;   isdx = 1; }
    else if (g < 26000) { E = Ed3; out = pd3; loc = g - 6000;   isdx = 1; }
    else if (g < 26100) { E = Er1; out = pr1; loc = g - 26000;  isdx = 0; }
    else if (g < 26600) { E = Er2; out = pr2; loc = g - 26100;  isdx = 0; }
    else if (g < 28600) { E = Er3; out = pr3; loc = g - 26600;  isdx = 0; }
    else                { E = Er4; out = pr4; loc = g - 28600;  isdx = 0; }
    const float* Wlo = isdx ? We_dx : We_rx;
    const float* Whi = Wlo + CD;
    const float* Wev = isdx ? Wev_dx : Wev_rx;
    float2 e   = *(const float2*)(E + (size_t)loc * CD + lane * 2);
    float2 whi = *(const float2*)(Whi + lane * 2);
    float2 wlo = *(const float2*)(Wlo + lane * 2);
    float2 wev = *(const float2*)(Wev + lane * 2);
    float ph = e.x * whi.x + e.y * whi.y;
    float pl = e.x * wlo.x + e.y * wlo.y;
    float pw = e.x * wev.x + e.y * wev.y;
    #pragma unroll
    for (int off = 32; off; off >>= 1) {
        ph += __shfl_xor(ph, off, 64);
        pl += __shfl_xor(pl, off, 64);
        pw += __shfl_xor(pw, off, 64);
    }
    if (lane == 0) {
        out[(size_t)loc * 4 + 0] = ph;
        out[(size_t)loc * 4 + 1] = pl;
        out[(size_t)loc * 4 + 2] = pw;
        out[(size_t)loc * 4 + 3] = 0.f;
    }
}

// ---------------- fused weight transpose+bf16: qkv/ff1/ff2/ew1 ----------------
// tiles: qkv 768 (4x 8x24), ff1 2048 (4x 8x64), ff2 2048 (4x 64x8), ew1 48 (6x8)
__global__ __launch_bounds__(256) void wconv_all(
    const float* __restrict__ qkv_w, unsigned short* __restrict__ qkv_wt,
    const float* __restrict__ ff1w,  unsigned short* __restrict__ ff1_wt,
    const float* __restrict__ ff2w,  unsigned short* __restrict__ ff2_wt,
    const float* __restrict__ ew1,   unsigned short* __restrict__ ew1_t)
{
    __shared__ float t[32][33];
    int b = blockIdx.x;
    const float* src; unsigned short* dst; int K, N, ky, nx;
    if (b < 768) {                          // qkv: K=256 N=768
        int mat = b / 192, r = b % 192; ky = r / 24; nx = r % 24;
        K = 256; N = 768;
        src = qkv_w + (size_t)mat * K * N; dst = qkv_wt + (size_t)mat * N * K;
    } else if (b < 2816) {                  // ff1: K=256 N=2048
        b -= 768; int mat = b / 512, r = b % 512; ky = r / 64; nx = r % 64;
        K = 256; N = 2048;
        src = ff1w + (size_t)mat * K * N; dst = ff1_wt + (size_t)mat * N * K;
    } else if (b < 4864) {                  // ff2: K=2048 N=256
        b -= 2816; int mat = b / 512, r = b % 512; ky = r / 8; nx = r % 8;
        K = 2048; N = 256;
        src = ff2w + (size_t)mat * K * N; dst = ff2_wt + (size_t)mat * N * K;
    } else {                                // ew1: K=192 N=256
        b -= 4864; ky = b / 8; nx = b % 8;
        K = 192; N = 256;
        src = ew1; dst = ew1_t;
    }
    int k0 = ky * 32, n0 = nx * 32;
    int tx = threadIdx.x & 31, ty = threadIdx.x >> 5;
    #pragma unroll
    for (int r = ty; r < 32; r += 8) t[r][tx] = src[(size_t)(k0 + r) * N + n0 + tx];
    __syncthreads();
    #pragma unroll
    for (int r = ty; r < 32; r += 8) dst[(size_t)(n0 + r) * K + k0 + tx] = f2b(t[tx][r]);
}

// ---------------- GRAM (+ fused build_x0: writes A0bf directly) ----------------
__global__ __launch_bounds__(256) void gram_kernel(
    const int* __restrict__ xd1, const int* __restrict__ xd2, const int* __restrict__ xd3,
    const int* __restrict__ xr1, const int* __restrict__ xr2, const int* __restrict__ xr3,
    const int* __restrict__ xr4,
    const float* __restrict__ Ed1, const float* __restrict__ Ed2, const float* __restrict__ Ed3,
    const float* __restrict__ Er1, const float* __restrict__ Er2, const float* __restrict__ Er3,
    const float* __restrict__ Er4,
    const float* __restrict__ pd1, const float* __restrict__ pd2, const float* __restrict__ pd3,
    const float* __restrict__ pr1, const float* __restrict__ pr2, const float* __restrict__ pr3,
    const float* __restrict__ pr4,
    const float* __restrict__ be_dx, const float* __restrict__ be_rx,
    const float* __restrict__ bev_dx, const float* __restrict__ bev_rx,
    const float* __restrict__ x_demo, const float* __restrict__ W_demo,
    const float* __restrict__ b_demo,
    unsigned short* __restrict__ A0bf)
{
    __shared__ float aw[96][4];
    __shared__ float ev[96];
    __shared__ int   sidx[96][4];
    __shared__ float part[4][128];
    const int nv   = blockIdx.x;
    const int tid  = threadIdx.x;
    const int wave = tid >> 6, lane = tid & 63;
    const int base = nv * DD;

    if (tid < 48) {
        const int d = tid;
        const int i1 = xd1[base + d], i2 = xd2[base + d], i3 = xd3[base + d];
        sidx[d][0] = i1; sidx[d][1] = i2; sidx[d][2] = i3;
        float4 q1 = *(const float4*)(pd1 + (size_t)i1 * 4);
        float4 q2 = *(const float4*)(pd2 + (size_t)i2 * 4);
        float4 q3 = *(const float4*)(pd3 + (size_t)i3 * 4);
        const float be = be_dx[0];
        const float p0 = q3.y;
        float s1 = fmaxf(p0 + q1.x + be, 0.f);
        float s2 = fmaxf(p0 + q2.x + be, 0.f);
        float s3 = fmaxf(p0 + q3.x + be, 0.f);
        float a1, a2, a3;
        if (i1 != 0) {
            float mx = fmaxf(s1, fmaxf(s2, s3));
            a1 = expf(s1 - mx); a2 = expf(s2 - mx); a3 = expf(s3 - mx);
        } else {
            a1 = a2 = a3 = 1.f;
        }
        float inv = 1.f / (a1 + a2 + a3);
        a1 *= inv; a2 *= inv; a3 *= inv;
        aw[d][0] = a1; aw[d][1] = a2; aw[d][2] = a3; aw[d][3] = 0.f;
        ev[d] = (i1 != 0) ? (a1 * q1.z + a2 * q2.z + a3 * q3.z + bev_dx[0]) : -1e20f;
    } else if (tid >= 64 && tid < 112) {
        const int d = tid - 64;
        const int i1 = xr1[base + d], i2 = xr2[base + d], i3 = xr3[base + d], i4 = xr4[base + d];
        const int m = 48 + d;
        sidx[m][0] = i1; sidx[m][1] = i2; sidx[m][2] = i3; sidx[m][3] = i4;
        float4 q1 = *(const float4*)(pr1 + (size_t)i1 * 4);
        float4 q2 = *(const float4*)(pr2 + (size_t)i2 * 4);
        float4 q3 = *(const float4*)(pr3 + (size_t)i3 * 4);
        float4 q4 = *(const float4*)(pr4 + (size_t)i4 * 4);
        const float be = be_rx[0];
        const float p0 = q4.y;
        float s1 = fmaxf(p0 + q1.x + be, 0.f);
        float s2 = fmaxf(p0 + q2.x + be, 0.f);
        float s3 = fmaxf(p0 + q3.x + be, 0.f);
        float s4 = fmaxf(p0 + q4.x + be, 0.f);
        float a1, a2, a3, a4;
        if (i1 != 0) {
            float mx = fmaxf(fmaxf(s1, s2), fmaxf(s3, s4));
            a1 = expf(s1 - mx); a2 = expf(s2 - mx); a3 = expf(s3 - mx); a4 = expf(s4 - mx);
        } else {
            a1 = a2 = a3 = a4 = 1.f;
        }
        float inv = 1.f / (a1 + a2 + a3 + a4);
        aw[m][0] = a1 * inv; aw[m][1] = a2 * inv; aw[m][2] = a3 * inv; aw[m][3] = a4 * inv;
        ev[m] = (i1 != 0) ? ((a1 * q1.z + a2 * q2.z + a3 * q3.z + a4 * q4.z) * inv + bev_rx[0])
                          : -1e20f;
    }
    __syncthreads();

    if (wave == 0) {
        float a = ev[lane];
        float b = (lane < 32) ? ev[64 + lane] : -3.0e38f;
        float mx = fmaxf(a, b);
        #pragma unroll
        for (int off = 32; off; off >>= 1) mx = fmaxf(mx, __shfl_xor(mx, off, 64));
        float ea = expf(a - mx);
        float eb = (lane < 32) ? expf(b - mx) : 0.f;
        float s = ea + eb;
        #pragma unroll
        for (int off = 32; off; off >>= 1) s += __shfl_xor(s, off, 64);
        float inv = 1.f / s;
        ev[lane] = ea * inv;
        if (lane < 32) ev[64 + lane] = eb * inv;
    }
    __syncthreads();

    if (tid < 96) {
        float av = ev[tid];
        aw[tid][0] *= av; aw[tid][1] *= av; aw[tid][2] *= av; aw[tid][3] *= av;
    }
    __syncthreads();

    float accx = 0.f, accy = 0.f;
    const int co = lane * 2;
    for (int m = wave; m < 96; m += 4) {
        if (m < 48) {
            int i1 = sidx[m][0], i2 = sidx[m][1], i3 = sidx[m][2];
            float2 e1 = *(const float2*)(Ed1 + (size_t)i1 * CD + co);
            float2 e2 = *(const float2*)(Ed2 + (size_t)i2 * CD + co);
            float2 e3 = *(const float2*)(Ed3 + (size_t)i3 * CD + co);
            float w1 = aw[m][0], w2 = aw[m][1], w3 = aw[m][2];
            accx += w1 * e1.x + w2 * e2.x + w3 * e3.x;
            accy += w1 * e1.y + w2 * e2.y + w3 * e3.y;
        } else {
            int i1 = sidx[m][0], i2 = sidx[m][1], i3 = sidx[m][2], i4 = sidx[m][3];
            float2 e1 = *(const float2*)(Er1 + (size_t)i1 * CD + co);
            float2 e2 = *(const float2*)(Er2 + (size_t)i2 * CD + co);
            float2 e3 = *(const float2*)(Er3 + (size_t)i3 * CD + co);
            float2 e4 = *(const float2*)(Er4 + (size_t)i4 * CD + co);
            float w1 = aw[m][0], w2 = aw[m][1], w3 = aw[m][2], w4 = aw[m][3];
            accx += w1 * e1.x + w2 * e2.x + w3 * e3.x + w4 * e4.x;
            accy += w1 * e1.y + w2 * e2.y + w3 * e3.y + w4 * e4.y;
        }
    }
    part[wave][co]     = accx;
    part[wave][co + 1] = accy;
    __syncthreads();
    // fused build_x0: A0bf[nv][192] = [relu(demo GEMM), ccv]
    if (tid < CD) {
        A0bf[(size_t)nv * 192 + 64 + tid] =
            f2b(part[0][tid] + part[1][tid] + part[2][tid] + part[3][tid]);
    } else if (tid >= 192) {
        int j = tid - 192;
        float acc = b_demo[j];
        #pragma unroll
        for (int f = 0; f < 32; ++f) acc += x_demo[nv * 32 + f] * W_demo[f * 64 + j];
        A0bf[(size_t)nv * 192 + j] = f2b(fmaxf(acc, 0.f));
    }
}

// ---------------- bf16 MFMA GEMM (64x64 tile, BK=32, 4 waves, split-K capable) ----------------
__global__ __launch_bounds__(256) void gemm_bf(
    const unsigned short* __restrict__ A, const unsigned short* __restrict__ B,
    const float* __restrict__ bias, const float* __restrict__ pe,
    float* __restrict__ Cf, unsigned short* __restrict__ Cb,
    int M, int N, int K, int flags, int kchunk)
{
    __shared__ unsigned short As[64][40];
    __shared__ unsigned short Bs[64][40];
    const int bm = blockIdx.y * 64, bn = blockIdx.x * 64;
    const int tid = threadIdx.x;
    const int wave = tid >> 6, lane = tid & 63;
    const int wr = (wave >> 1) * 32, wc = (wave & 1) * 32;
    const int l15 = lane & 15, l4 = lane >> 4;
    const int srow = tid >> 2, sk8 = (tid & 3) * 8;
    const int kbeg = blockIdx.z * kchunk, kend = kbeg + kchunk;
    f32x4 acc[2][2] = {};

    for (int k0 = kbeg; k0 < kend; k0 += 32) {
        *(short8v*)&As[srow][sk8] = *(const short8v*)(A + (size_t)(bm + srow) * K + k0 + sk8);
        *(short8v*)&Bs[srow][sk8] = *(const short8v*)(B + (size_t)(bn + srow) * K + k0 + sk8);
        __syncthreads();
        short8v a0 = *(const short8v*)&As[wr + l15][l4 * 8];
        short8v a1 = *(const short8v*)&As[wr + 16 + l15][l4 * 8];
        short8v b0 = *(const short8v*)&Bs[wc + l15][l4 * 8];
        short8v b1 = *(const short8v*)&Bs[wc + 16 + l15][l4 * 8];
        acc[0][0] = __builtin_amdgcn_mfma_f32_16x16x32_bf16(a0, b0, acc[0][0], 0, 0, 0);
        acc[0][1] = __builtin_amdgcn_mfma_f32_16x16x32_bf16(a0, b1, acc[0][1], 0, 0, 0);
        acc[1][0] = __builtin_amdgcn_mfma_f32_16x16x32_bf16(a1, b0, acc[1][0], 0, 0, 0);
        acc[1][1] = __builtin_amdgcn_mfma_f32_16x16x32_bf16(a1, b1, acc[1][1], 0, 0, 0);
        __syncthreads();
    }

    if (gridDim.z == 1) {
        #pragma unroll
        for (int mi = 0; mi < 2; ++mi)
            #pragma unroll
            for (int ni = 0; ni < 2; ++ni) {
                int col = bn + wc + ni * 16 + l15;
                float bz = (flags & GF_BIAS) ? bias[col] : 0.f;
                #pragma unroll
                for (int r = 0; r < 4; ++r) {
                    int row = bm + wr + mi * 16 + l4 * 4 + r;
                    float v = acc[mi][ni][r] + bz;
                    if (flags & GF_PE)   v += pe[(row % VIS) * N + col];
                    if (flags & GF_RELU) v = fmaxf(v, 0.f);
                    if (Cf) Cf[(size_t)row * N + col] = v;
                    if (Cb) Cb[(size_t)row * N + col] = f2b(v);
                }
            }
    } else {
        float* Cp = Cf + (size_t)blockIdx.z * M * N;
        #pragma unroll
        for (int mi = 0; mi < 2; ++mi)
            #pragma unroll
            for (int ni = 0; ni < 2; ++ni) {
                int col = bn + wc + ni * 16 + l15;
                #pragma unroll
                for (int r = 0; r < 4; ++r) {
                    int row = bm + wr + mi * 16 + l4 * 4 + r;
                    Cp[(size_t)row * N + col] = acc[mi][ni][r];
                }
            }
    }
}

// ---------------- f32 tiled GEMM (enc_w2; split-K raw partials) ----------------
__global__ __launch_bounds__(256) void gemm_k(
    const float* __restrict__ A, const float* __restrict__ B,
    float* __restrict__ C, int M, int N, int K, int kchunk)
{
    __shared__ float As[16][68];
    __shared__ float Bs[16][64];
    const int bm = blockIdx.y * 64, bn = blockIdx.x * 64;
    const int tid = threadIdx.x;
    const int tx = tid & 15, ty = tid >> 4;
    const int kbeg = blockIdx.z * kchunk;
    const int kend = kbeg + kchunk;
    const int ar  = tid >> 2, akc = (tid & 3) * 4;
    const int bbr = tid >> 4, bbc = (tid & 15) * 4;
    float acc[4][4] = {{0.f}};

    for (int k0 = kbeg; k0 < kend; k0 += 16) {
        float4 va = *(const float4*)(A + (size_t)(bm + ar) * K + k0 + akc);
        float4 vb = *(const float4*)(B + (size_t)(k0 + bbr) * N + bn + bbc);
        As[akc + 0][ar] = va.x;
        As[akc + 1][ar] = va.y;
        As[akc + 2][ar] = va.z;
        As[akc + 3][ar] = va.w;
        *(float4*)&Bs[bbr][bbc] = vb;
        __syncthreads();
        #pragma unroll
        for (int kk = 0; kk < 16; ++kk) {
            float4 a = *(const float4*)&As[kk][ty * 4];
            float4 b = *(const float4*)&Bs[kk][tx * 4];
            acc[0][0] += a.x * b.x; acc[0][1] += a.x * b.y; acc[0][2] += a.x * b.z; acc[0][3] += a.x * b.w;
            acc[1][0] += a.y * b.x; acc[1][1] += a.y * b.y; acc[1][2] += a.y * b.z; acc[1][3] += a.y * b.w;
            acc[2][0] += a.z * b.x; acc[2][1] += a.z * b.y; acc[2][2] += a.z * b.z; acc[2][3] += a.z * b.w;
            acc[3][0] += a.w * b.x; acc[3][1] += a.w * b.y; acc[3][2] += a.w * b.z; acc[3][3] += a.w * b.w;
        }
        __syncthreads();
    }

    float* Cp = C + (size_t)blockIdx.z * M * N;
    #pragma unroll
    for (int i = 0; i < 4; ++i) {
        int row = bm + ty * 4 + i;
        *(float4*)(Cp + (size_t)row * N + bn + tx * 4) = *(float4*)&acc[i][0];
    }
}

// ---------------- split-K reduce + bias + resid + LN ; bf16 mirror (used for LN2) ----------------
__global__ void reduce_kernel(
    const float* __restrict__ part, int S, int MN,
    const float* __restrict__ bias,
    const float* __restrict__ resid,
    const float* __restrict__ lns, const float* __restrict__ lnb,
    int N, float* __restrict__ out, unsigned short* __restrict__ out_bf)
{
    const int row = blockIdx.x, t = threadIdx.x;
    const size_t idx = (size_t)row * N + t;
    float v = bias[t];
    for (int s = 0; s < S; ++s) v += part[(size_t)s * MN + idx];
    if (resid) v += resid[idx];
    if (lns) {
        float s1 = v, s2 = v * v;
        #pragma unroll
        for (int off = 32; off; off >>= 1) {
            s1 += __shfl_xor(s1, off, 64);
            s2 += __shfl_xor(s2, off, 64);
        }
        __shared__ float red[2][4];
        const int wave = t >> 6, lane = t & 63, nw = blockDim.x >> 6;
        if (lane == 0) { red[0][wave] = s1; red[1][wave] = s2; }
        __syncthreads();
        s1 = 0.f; s2 = 0.f;
        for (int w = 0; w < nw; ++w) { s1 += red[0][w]; s2 += red[1][w]; }
        float invn = 1.f / (float)N;
        float m    = s1 * invn;
        float var  = s2 * invn - m * m;
        float inv  = 1.f / sqrtf(var + 1e-5f);
        v = (v - m) * inv * lns[t] + lnb[t];
    }
    out[idx] = v;
    if (out_bf) out_bf[idx] = f2b(v);
}

// ---------------- fused attention + proj + residual + LN1 ; block per patient ----------------
__global__ __launch_bounds__(256) void attn_proj_ln(
    const float* __restrict__ qkv,      // [N*VIS][768], bias applied
    const float* __restrict__ ow,       // f32 [256][256]
    const float* __restrict__ ob,
    const float* __restrict__ lns, const float* __restrict__ lnb,
    float* __restrict__ xbuf, unsigned short* __restrict__ xbuf_bf)
{
    __shared__ float attn_s[VIS][DT];   // 5 KB
    __shared__ float red[VIS][2][4];
    const int n = blockIdx.x;
    const int tid = threadIdx.x;
    const int h = tid >> 5, t = tid & 31;
    const int ch = h * HD + t;

    {   // ---- attention (8 heads x 32 threads), results to LDS ----
        float q[VIS], k[VIS], v[VIS];
        #pragma unroll
        for (int j = 0; j < VIS; ++j) {
            const float* row = qkv + (size_t)(n * VIS + j) * 768 + ch;
            q[j] = row[0]; k[j] = row[256]; v[j] = row[512];
        }
        const float scale = 0.1767766952966369f;  // 1/sqrt(32)
        float sm[VIS][VIS];
        #pragma unroll
        for (int qi = 0; qi < VIS; ++qi)
            #pragma unroll
            for (int ki = 0; ki < VIS; ++ki) {
                float p = q[qi] * k[ki];
                #pragma unroll
                for (int off = 16; off; off >>= 1) p += __shfl_xor(p, off, 32);
                sm[qi][ki] = p * scale;
            }
        #pragma unroll
        for (int qi = 0; qi < VIS; ++qi) {
            float mx = sm[qi][0];
            #pragma unroll
            for (int ki = 1; ki < VIS; ++ki) mx = fmaxf(mx, sm[qi][ki]);
            float e[VIS], sum = 0.f;
            #pragma unroll
            for (int ki = 0; ki < VIS; ++ki) { e[ki] = expf(sm[qi][ki] - mx); sum += e[ki]; }
            float inv = 1.f / sum;
            float acc = 0.f;
            #pragma unroll
            for (int ki = 0; ki < VIS; ++ki) acc += e[ki] * inv * v[ki];
            attn_s[qi][ch] = acc;
        }
    }
    __syncthreads();

    // ---- proj: thread owns output col c; f32 weights, coalesced per-k row reads ----
    const int c = tid;
    float acc[VIS] = {0.f, 0.f, 0.f, 0.f, 0.f};
    #pragma unroll 4
    for (int k = 0; k < DT; ++k) {
        float w = ow[(size_t)k * DT + c];
        #pragma unroll
        for (int j = 0; j < VIS; ++j) acc[j] += attn_s[j][k] * w;
    }
    float bz = ob[c];
    float v[VIS];
    #pragma unroll
    for (int j = 0; j < VIS; ++j)
        v[j] = acc[j] + bz + xbuf[(size_t)(n * VIS + j) * DT + c];

    // ---- LN per row (all 5 rows in-block) ----
    const int wave = tid >> 6, lane = tid & 63;
    #pragma unroll
    for (int j = 0; j < VIS; ++j) {
        float s1 = v[j], s2 = v[j] * v[j];
        #pragma unroll
        for (int off = 32; off; off >>= 1) {
            s1 += __shfl_xor(s1, off, 64);
            s2 += __shfl_xor(s2, off, 64);
        }
        if (lane == 0) { red[j][0][wave] = s1; red[j][1][wave] = s2; }
    }
    __syncthreads();
    #pragma unroll
    for (int j = 0; j < VIS; ++j) {
        float s1 = red[j][0][0] + red[j][0][1] + red[j][0][2] + red[j][0][3];
        float s2 = red[j][1][0] + red[j][1][1] + red[j][1][2] + red[j][1][3];
        float m   = s1 * (1.f / 256.f);
        float var = s2 * (1.f / 256.f) - m * m;
        float inv = 1.f / sqrtf(var + 1e-5f);
        float o = (v[j] - m) * inv * lns[c] + lnb[c];
        size_t idx = (size_t)(n * VIS + j) * DT + c;
        xbuf[idx] = o;
        xbuf_bf[idx] = f2b(o);
    }
}

// ---------------- visit compression + ph MLP (absorbs enc split-K reduce) ----------------
__global__ __launch_bounds__(128) void vc_ph_kernel(
    const float* __restrict__ encp, int S, int MN, const float* __restrict__ enc_b2,
    const float* __restrict__ Wcv, const float* __restrict__ bcv,
    const float* __restrict__ mlp_w, const float* __restrict__ mlp_b,
    const float* __restrict__ mlp2_w, const float* __restrict__ mlp2_b,
    float* __restrict__ civ_out, float* __restrict__ ph_out)
{
    const int n = blockIdx.x, t = threadIdx.x;
    const int wave = t >> 6, lane = t & 63;
    float e[VIS];
    #pragma unroll
    for (int v = 0; v < VIS; ++v) {
        size_t idx = (size_t)(n * VIS + v) * REP + t;
        float ev = enc_b2[t];
        for (int s = 0; s < S; ++s) ev += encp[(size_t)s * MN + idx];
        e[v] = ev;
    }
    float w = Wcv[t];
    __shared__ float part[VIS][2];
    #pragma unroll
    for (int v = 0; v < VIS; ++v) {
        float pv = e[v] * w;
        #pragma unroll
        for (int off = 32; off; off >>= 1) pv += __shfl_xor(pv, off, 64);
        if (lane == 0) part[v][wave] = pv;
    }
    __syncthreads();
    float b0 = bcv[0];
    float sc[VIS], mx = -3e38f;
    #pragma unroll
    for (int v = 0; v < VIS; ++v) { sc[v] = part[v][0] + part[v][1] + b0; mx = fmaxf(mx, sc[v]); }
    float sum = 0.f;
    #pragma unroll
    for (int v = 0; v < VIS; ++v) { sc[v] = expf(sc[v] - mx); sum += sc[v]; }
    float inv = 1.f / sum;
    float civ = 0.f;
    #pragma unroll
    for (int v = 0; v < VIS; ++v) civ += sc[v] * inv * e[v];
    civ_out[(size_t)n * REP + t] = civ;

    __shared__ float civ_s[REP];
    __shared__ float h1_s[64];
    civ_s[t] = civ;
    __syncthreads();
    if (t < 64) {
        float acc = mlp_b[t];
        #pragma unroll 8
        for (int c = 0; c < REP; ++c) acc += civ_s[c] * mlp_w[c * 64 + t];
        h1_s[t] = fmaxf(acc, 0.f);
    }
    __syncthreads();
    if (t < 64) {
        float acc = mlp2_b[t];
        #pragma unroll 8
        for (int j = 0; j < 64; ++j) acc += h1_s[j] * mlp2_w[j * 64 + t];
        ph_out[(size_t)n * 64 + t] = acc;
    }
}

// ---------------- per-event FC heads ----------------
__global__ __launch_bounds__(256) void heads_kernel(
    const float* __restrict__ civ,
    const float* __restrict__ fc1w, const float* __restrict__ fc1b,
    const float* __restrict__ fc2w, const float* __restrict__ fc2b,
    const float* __restrict__ fc3w, const float* __restrict__ fc3b,
    float* __restrict__ out)
{
    const int n = blockIdx.x >> 1, e = blockIdx.x & 1;
    const int t = threadIdx.x;
    __shared__ float civ_s[REP], h1[256], h2[128];
    if (t < REP) civ_s[t] = civ[(size_t)n * REP + t];
    __syncthreads();
    {
        float acc = fc1b[e * 256 + t];
        const float* w = fc1w + (size_t)e * REP * 256;
        #pragma unroll 8
        for (int c = 0; c < REP; ++c) acc += civ_s[c] * w[c * 256 + t];
        h1[t] = fmaxf(acc, 0.f);
    }
    __syncthreads();
    if (t < 128) {
        float acc = fc2b[e * 128 + t];
        const float* w = fc2w + (size_t)e * 256 * 128;
        #pragma unroll 8
        for (int c = 0; c < 256; ++c) acc += h1[c] * w[c * 128 + t];
        h2[t] = fmaxf(acc, 0.f);
    }
    __syncthreads();
    if (t < 64) {
        float acc = fc3b[e * 64 + t];
        const float* w = fc3w + (size_t)e * 128 * 64;
        #pragma unroll 8
        for (int c = 0; c < 128; ++c) acc += h2[c] * w[c * 64 + t];
        out[(size_t)(n * 2 + e) * 64 + t] = 1.f / (1.f + expf(-acc));
    }
}

// ---------------- launch ----------------
extern "C" void kernel_launch(void* const* d_in, const int* in_sizes, int n_in,
                              void* d_out, int out_size, void* d_ws, size_t ws_size,
                              hipStream_t stream) {
    const int*   xd1    = (const int*)  d_in[0];
    const int*   xd2    = (const int*)  d_in[1];
    const int*   xd3    = (const int*)  d_in[2];
    const int*   xr1    = (const int*)  d_in[3];
    const int*   xr2    = (const int*)  d_in[4];
    const int*   xr3    = (const int*)  d_in[5];
    const int*   xr4    = (const int*)  d_in[6];
    const float* x_demo = (const float*)d_in[7];
    const float* W_demo = (const float*)d_in[8];
    const float* b_demo = (const float*)d_in[9];
    const float* Ed1    = (const float*)d_in[10];
    const float* Ed2    = (const float*)d_in[11];
    const float* Ed3    = (const float*)d_in[12];
    const float* Er1    = (const float*)d_in[13];
    const float* Er2    = (const float*)d_in[14];
    const float* Er3    = (const float*)d_in[15];
    const float* Er4    = (const float*)d_in[16];
    const float* We_dx  = (const float*)d_in[17];
    const float* be_dx  = (const float*)d_in[18];
    const float* We_rx  = (const float*)d_in[19];
    const float* be_rx  = (const float*)d_in[20];
    const float* Wev_dx = (const float*)d_in[21];
    const float* bev_dx = (const float*)d_in[22];
    const float* Wev_rx = (const float*)d_in[23];
    const float* bev_rx = (const float*)d_in[24];
    const float* Wcv    = (const float*)d_in[25];
    const float* bcv    = (const float*)d_in[26];
    const float* enc_w1 = (const float*)d_in[27];
    const float* enc_b1 = (const float*)d_in[28];
    const float* qkv_w  = (const float*)d_in[29];
    const float* qkv_b  = (const float*)d_in[30];
    const float* ow     = (const float*)d_in[31];
    const float* ob     = (const float*)d_in[32];
    const float* ln1s   = (const float*)d_in[33];
    const float* ln1b   = (const float*)d_in[34];
    const float* ff1w   = (const float*)d_in[35];
    const float* ff1b   = (const float*)d_in[36];
    const float* ff2w   = (const float*)d_in[37];
    const float* ff2b   = (const float*)d_in[38];
    const float* ln2s   = (const float*)d_in[39];
    const float* ln2b   = (const float*)d_in[40];
    const float* enc_w2 = (const float*)d_in[41];
    const float* enc_b2 = (const float*)d_in[42];
    const float* mlp_w  = (const float*)d_in[43];
    const float* mlp_b  = (const float*)d_in[44];
    const float* mlp2_w = (const float*)d_in[45];
    const float* mlp2_b = (const float*)d_in[46];
    const float* fc1w   = (const float*)d_in[47];
    const float* fc1b   = (const float*)d_in[48];
    const float* fc2w   = (const float*)d_in[49];
    const float* fc2b   = (const float*)d_in[50];
    const float* fc3w   = (const float*)d_in[51];
    const float* fc3b   = (const float*)d_in[52];

    // workspace (~29 MB of the ~256 MiB d_ws)
    float* ws     = (float*)d_ws;
    float* pe     = ws;                       // 1,280
    float* xbuf   = pe + 1280;                // 327,680
    float* qkvbuf = xbuf + 327680;            // 983,040
    float* buf2   = qkvbuf + 983040;          // 1,310,720 (ff2 z=4 / enc_w2 z=8 partials)
    float* ptab   = buf2 + 1310720;           // 134,400 (projection tables)
    unsigned short* usb = (unsigned short*)(ptab + 134400);
    unsigned short* A0bf    = usb;                     // 245,760
    unsigned short* xbuf_bf = A0bf + 245760;           // 327,680
    unsigned short* ff1_bf  = xbuf_bf + 327680;        // 2,621,440
    unsigned short* qkv_wt  = ff1_bf + 2621440;        // 786,432   [768][256] x4
    unsigned short* ff1_wt  = qkv_wt + 786432;         // 2,097,152 [2048][256] x4
    unsigned short* ff2_wt  = ff1_wt + 2097152;        // 2,097,152 [256][2048] x4
    unsigned short* ew1_t   = ff2_wt + 2097152;        // 49,152    [256][192]

    float* pd1 = ptab;
    float* pd2 = pd1 + 4000;
    float* pd3 = pd2 + 20000;
    float* pr1 = pd3 + 80000;
    float* pr2 = pr1 + 400;
    float* pr3 = pr2 + 2000;
    float* pr4 = pr3 + 8000;

    // prologue: 3 dispatches (was 13)
    prep_kernel<<<5 + 8400, 256, 0, stream>>>(Ed1, Ed2, Ed3, Er1, Er2, Er3, Er4,
                                              We_dx, We_rx, Wev_dx, Wev_rx,
                                              pe, pd1, pd2, pd3, pr1, pr2, pr3, pr4);
    wconv_all<<<4912, 256, 0, stream>>>(qkv_w, qkv_wt, ff1w, ff1_wt, ff2w, ff2_wt,
                                        enc_w1, ew1_t);
    gram_kernel<<<NV, 256, 0, stream>>>(xd1, xd2, xd3, xr1, xr2, xr3, xr4,
                                        Ed1, Ed2, Ed3, Er1, Er2, Er3, Er4,
                                        pd1, pd2, pd3, pr1, pr2, pr3, pr4,
                                        be_dx, be_rx, bev_dx, bev_rx,
                                        x_demo, W_demo, b_demo, A0bf);

    // x = A0 @ enc_w1 + b + pe (MFMA)
    gemm_bf<<<dim3(4, 20, 1), 256, 0, stream>>>(A0bf, ew1_t, enc_b1, pe,
                                                xbuf, xbuf_bf, NV, DT, 192,
                                                GF_BIAS | GF_PE, 192);

    for (int i = 0; i < 4; ++i) {
        // qkv (MFMA, bias fused): [1280,768] K=256
        gemm_bf<<<dim3(12, 20, 1), 256, 0, stream>>>(
            xbuf_bf, qkv_wt + (size_t)i * 768 * 256, qkv_b + i * 768, nullptr,
            qkvbuf, nullptr, NV, 768, DT, GF_BIAS, DT);
        // fused attention + proj(f32) + residual + LN1
        attn_proj_ln<<<N_PAT, 256, 0, stream>>>(
            qkvbuf, ow + (size_t)i * DT * DT, ob + i * DT,
            ln1s + i * DT, ln1b + i * DT, xbuf, xbuf_bf);
        // ff1 (MFMA, bias+relu): [1280,2048] K=256
        gemm_bf<<<dim3(32, 20, 1), 256, 0, stream>>>(
            xbuf_bf, ff1_wt + (size_t)i * DFF * 256, ff1b + i * DFF, nullptr,
            nullptr, ff1_bf, NV, DFF, DT, GF_BIAS | GF_RELU, DT);
        // ff2 (MFMA split-K z=4): [1280,256] K=2048
        gemm_bf<<<dim3(4, 20, 4), 256, 0, stream>>>(
            ff1_bf, ff2_wt + (size_t)i * 256 * DFF, nullptr, nullptr,
            buf2, nullptr, NV, DT, DFF, 0, 512);
        // + ff2b + residual -> LN2 -> xbuf / xbuf_bf
        reduce_kernel<<<NV, DT, 0, stream>>>(buf2, 4, NV * DT, ff2b + i * DT,
                                             xbuf, ln2s + i * DT, ln2b + i * DT,
                                             DT, xbuf, xbuf_bf);
    }

    // enc: f32 split-K z=8 raw partials; vc_ph sums them
    gemm_k<<<dim3(2, 20, 8), 256, 0, stream>>>(xbuf, enc_w2, buf2, NV, REP, DT, 32);

    float* civ_out = (float*)d_out + 32768;
    float* ph_out  = (float*)d_out + 65536;
    vc_ph_kernel<<<N_PAT, 128, 0, stream>>>(buf2, 8, NV * REP, enc_b2,
                                            Wcv, bcv, mlp_w, mlp_b, mlp2_w, mlp2_b,
                                            civ_out, ph_out);
    heads_kernel<<<N_PAT * 2, 256, 0, stream>>>(civ_out, fc1w, fc1b, fc2w, fc2b, fc3w, fc3b,
                                                (float*)d_out);
}